// Round 1
// baseline (17895.117 us; speedup 1.0000x reference)
//
#include <hip/hip_runtime.h>

#define B_ 256
#define T_ 128
#define V_ 42
#define LAT_ 200
#define U_ 512
#define G4_ 2048

typedef __attribute__((ext_vector_type(8))) short bf8;
typedef __attribute__((ext_vector_type(4))) float f4;

__device__ __forceinline__ float bf2f(unsigned short u) {
  union { unsigned int i; float f; } v; v.i = ((unsigned int)u) << 16; return v.f;
}
__device__ __forceinline__ unsigned short f2bf(float f) {
  union { float f; unsigned int i; } v; v.f = f;
  unsigned int r = v.i + 0x7fffu + ((v.i >> 16) & 1u);
  return (unsigned short)(r >> 16);
}
__device__ __forceinline__ float sigf(float x) { return 1.f / (1.f + __expf(-x)); }

// ---------------------------------------------------------------------------
// Weight swizzle: W[k(512)][n(2048)] fp32 -> bf16 fragments laid out so each
// lane's 8 B-elements (n = lane&15, k = (lane>>4)*8 + j) are 16B-contiguous
// and a wave's 64 lanes read one contiguous 1KB block.
// ---------------------------------------------------------------------------
struct SwzParams { const float* src[10]; unsigned short* dst; };

__global__ __launch_bounds__(256) void swizzle_kernel(SwzParams sp) {
  int b = blockIdx.x;
  int mat = b >> 7, nt16 = b & 127;
  const float* src = sp.src[mat];
  unsigned short* dst = sp.dst + (size_t)mat * ((size_t)U_ * G4_);
  int tid = threadIdx.x;
  int g = tid >> 6, lane = tid & 63;
  int n = nt16 * 16 + (lane & 15);
  int kq = (lane >> 4) * 8;
  for (int it = 0; it < 4; it++) {
    int kt = g * 4 + it;
    int kb = kt * 32 + kq;
    unsigned short o[8];
#pragma unroll
    for (int j = 0; j < 8; j++) o[j] = f2bf(src[(size_t)(kb + j) * G4_ + n]);
    *(uint4*)(dst + ((size_t)(nt16 * 16 + kt) * 64 + lane) * 8) = *(const uint4*)o;
  }
}

// table[v][j] = sum_n emb[v,n] * k0[roff+n][j]   (layer-0 token contribution)
__global__ __launch_bounds__(256) void table_kernel(const float* emb, const float* k0, int roff, float* table) {
  int v = blockIdx.x, tid = threadIdx.x;
  __shared__ float e[LAT_];
  for (int i = tid; i < LAT_; i += 256) e[i] = emb[v * LAT_ + i];
  __syncthreads();
  for (int j = tid; j < G4_; j += 256) {
    float s = 0.f;
    for (int n = 0; n < LAT_; n++) s += e[n] * k0[(size_t)(roff + n) * G4_ + j];
    table[v * G4_ + j] = s;
  }
}

// cvec[b][j] = enc_b0[j] + sum_p C[b,p]*enc_k0[200+p][j]
__global__ __launch_bounds__(256) void cvec_kernel(const float* C, const float* k0, const float* b0, float* cv) {
  int b = blockIdx.x, tid = threadIdx.x;
  float c0 = C[b * 3], c1 = C[b * 3 + 1], c2 = C[b * 3 + 2];
  for (int j = tid; j < G4_; j += 256)
    cv[b * G4_ + j] = b0[j] + c0 * k0[(size_t)200 * G4_ + j] + c1 * k0[(size_t)201 * G4_ + j]
                            + c2 * k0[(size_t)202 * G4_ + j];
}

// VAE: mean/log_sigma from final encoder cell state; z; KL partial sum.
__global__ __launch_bounds__(256) void vae_kernel(const float* c2, const float* Wm, const float* bm,
                                                  const float* Ws, const float* bs, const float* eps,
                                                  float* zlat, float* lat_sum) {
  int b = blockIdx.x, tid = threadIdx.x;
  __shared__ float h[U_];
  __shared__ float red[256];
  for (int i = tid; i < U_; i += 256) h[i] = c2[b * U_ + i];
  __syncthreads();
  float contrib = 0.f;
  if (tid < LAT_) {
    float m = bm[tid], ls = bs[tid];
    for (int k = 0; k < U_; k++) { float hv = h[k]; m += hv * Wm[k * LAT_ + tid]; ls += hv * Ws[k * LAT_ + tid]; }
    zlat[b * LAT_ + tid] = m + expf(ls * 0.5f) * eps[b * LAT_ + tid];
    contrib = 1.f + ls - m * m - expf(ls);
  }
  red[tid] = contrib; __syncthreads();
  for (int s = 128; s > 0; s >>= 1) { if (tid < s) red[tid] += red[tid + s]; __syncthreads(); }
  if (tid == 0) atomicAdd(lat_sum, red[0]);
}

// dvec[b][j] = dec_b0[j] + sum_n z[b,n]*dk0[n][j] + sum_p C[b,p]*dk0[400+p][j]
__global__ __launch_bounds__(256) void dvec_kernel(const float* zlat, const float* C, const float* dk0,
                                                   const float* db0, float* dvec) {
  int b = blockIdx.x, tid = threadIdx.x;
  __shared__ float zr[LAT_];
  for (int i = tid; i < LAT_; i += 256) zr[i] = zlat[b * LAT_ + i];
  __syncthreads();
  float c0 = C[b * 3], c1 = C[b * 3 + 1], c2v = C[b * 3 + 2];
  for (int j = tid; j < G4_; j += 256) {
    float s = db0[j] + c0 * dk0[(size_t)400 * G4_ + j] + c1 * dk0[(size_t)401 * G4_ + j]
                     + c2v * dk0[(size_t)402 * G4_ + j];
    for (int n = 0; n < LAT_; n++) s += zr[n] * dk0[(size_t)n * G4_ + j];
    dvec[b * G4_ + j] = s;
  }
}

// ---------------------------------------------------------------------------
// Wavefront LSTM step. Grid: 3 layers x 128 tiles (+8 CE blocks, decoder only).
// Layer L processes t = s - L. Double-buffered h per layer (parity = s&1).
// Tile = 32 batch rows x 32 unit cols (x4 gates = 128 z-cols). 4 waves:
// wave w -> (mh=w>>1) 16 rows, (nh=w&1) 16 cols; acc = 4 gates x f32x4.
// ---------------------------------------------------------------------------
struct StepParams {
  const unsigned short *Wk1, *Wk2;        // swizzled input kernels (layers 1,2)
  const unsigned short *Wr0, *Wr1, *Wr2;  // swizzled recurrent kernels
  const float *b1, *b2;                   // biases layers 1,2
  const float *table;                     // [V,2048] layer-0 token additive
  const float *cvec;                      // [B,2048] layer-0 per-row additive (incl bias)
  const int *X;
  unsigned short *h0a, *h0b, *h1a, *h1b, *h2a, *h2b;  // bf16 [B,U] double buffers
  float *c0, *c1, *c2;                    // fp32 [B,U] cell states
  const float *Wo; const float *bo; const int *Y; const int *Lb; float *ce_sum;
  int s;
};

__global__ __launch_bounds__(256) void step_kernel(StepParams p) {
  __shared__ unsigned short smem[2 * 32 * 512];  // 64KB: [0]=h rows, [1]=x rows (xor-swizzled 16B chunks)
  const int tid = threadIdx.x;
  const int bid = blockIdx.x;
  const int cur = p.s & 1, prv = cur ^ 1;
  const int layer = bid >> 7;

  if (layer >= 3) {
    // ---- CE blocks (decoder only): t = s-3, consumes h2 written at s-1 ----
    int t = p.s - 3;
    if (t < 0 || t >= T_) return;
    int cb = bid - 384;
    const unsigned short* h2 = prv ? p.h2b : p.h2a;
    int r0 = cb * 32;
    for (int i = 0; i < 8; i++) {
      int idx = tid + i * 256, r = idx >> 6, ch = idx & 63;
      *(uint4*)(smem + r * 512 + ch * 8) = *(const uint4*)(h2 + (size_t)(r0 + r) * U_ + ch * 8);
    }
    __syncthreads();
    int lr = tid >> 3, sub = tid & 7;
    int rr = r0 + lr;
    int yv = p.Y[rr * T_ + t];
    float mx = -1e30f;
    float pre[6]; int cols[6]; int nc = 0;
    for (int c = sub; c < V_; c += 8) {
      float s = p.bo[c];
      for (int i = 0; i < U_; i++) {
        int k = (i + lr) & (U_ - 1);                 // row-offset start: bank-spread
        s += bf2f(smem[lr * 512 + k]) * p.Wo[k * V_ + c];
      }
      pre[nc] = s; cols[nc] = c; nc++;
      mx = fmaxf(mx, s);
    }
    for (int d = 1; d < 8; d <<= 1) mx = fmaxf(mx, __shfl_xor(mx, d));
    float se = 0.f, py = 0.f;
    for (int i = 0; i < nc; i++) { se += __expf(pre[i] - mx); if (cols[i] == yv) py = pre[i]; }
    for (int d = 1; d < 8; d <<= 1) { se += __shfl_xor(se, d); py += __shfl_xor(py, d); }
    if (sub == 0 && t < p.Lb[rr]) atomicAdd(p.ce_sum, mx + logf(se) - py);
    return;
  }

  int t = p.s - layer;
  if (t < 0 || t >= T_) return;
  const int tile = bid & 127;
  const int mt = tile & 7, nt = tile >> 3;

  unsigned short* hA[3] = {p.h0a, p.h1a, p.h2a};
  unsigned short* hB[3] = {p.h0b, p.h1b, p.h2b};
  float* cbuf[3] = {p.c0, p.c1, p.c2};
  const unsigned short* hin = prv ? hB[layer] : hA[layer];
  unsigned short* hout      = cur ? hB[layer] : hA[layer];

  // ---- stage h (and x = h of layer below) rows into LDS, xor-swizzled ----
  {
    const unsigned short* src = hin + (size_t)mt * 32 * U_;
    for (int i = 0; i < 8; i++) {
      int idx = tid + i * 256, r = idx >> 6, ch = idx & 63;
      int chs = ch ^ (r & 7);
      *(uint4*)(smem + (r * 64 + chs) * 8) = *(const uint4*)(src + r * U_ + ch * 8);
    }
    if (layer > 0) {
      const unsigned short* xin = (prv ? hB[layer - 1] : hA[layer - 1]) + (size_t)mt * 32 * U_;
      for (int i = 0; i < 8; i++) {
        int idx = tid + i * 256, r = idx >> 6, ch = idx & 63;
        int chs = ch ^ (r & 7);
        *(uint4*)(smem + 32 * 512 + (r * 64 + chs) * 8) = *(const uint4*)(xin + r * U_ + ch * 8);
      }
    }
  }
  __syncthreads();

  const int lane = tid & 63, wave = tid >> 6;
  const int mh = wave >> 1, nh = wave & 1;
  const int q = lane >> 4, l15 = lane & 15;
  const int mloc = mh * 16 + l15;
  const int ntb = nt * 2 + nh;  // 16-col tile index; gate g lives at ntb + g*32

  f4 acc0 = {0.f,0.f,0.f,0.f}, acc1 = {0.f,0.f,0.f,0.f}, acc2 = {0.f,0.f,0.f,0.f}, acc3 = {0.f,0.f,0.f,0.f};
  const int GSTRIDE = 32 * 16 * 64 * 8;  // ushort elems per gate group in swizzled W

  // recurrent GEMM: h @ rk
  {
    const unsigned short* Wr = layer == 0 ? p.Wr0 : (layer == 1 ? p.Wr1 : p.Wr2);
#pragma unroll 4
    for (int kk = 0; kk < 16; kk++) {
      int c = kk * 4 + q;
      bf8 a = *(const bf8*)(smem + (mloc * 64 + (c ^ (mloc & 7))) * 8);
      const unsigned short* wb = Wr + ((size_t)(ntb * 16 + kk) * 64 + lane) * 8;
      acc0 = __builtin_amdgcn_mfma_f32_16x16x32_bf16(a, *(const bf8*)(wb), acc0, 0, 0, 0);
      acc1 = __builtin_amdgcn_mfma_f32_16x16x32_bf16(a, *(const bf8*)(wb + GSTRIDE), acc1, 0, 0, 0);
      acc2 = __builtin_amdgcn_mfma_f32_16x16x32_bf16(a, *(const bf8*)(wb + 2 * GSTRIDE), acc2, 0, 0, 0);
      acc3 = __builtin_amdgcn_mfma_f32_16x16x32_bf16(a, *(const bf8*)(wb + 3 * GSTRIDE), acc3, 0, 0, 0);
    }
  }
  // input GEMM: x @ k (layers 1,2)
  if (layer > 0) {
    const unsigned short* Wk = layer == 1 ? p.Wk1 : p.Wk2;
#pragma unroll 4
    for (int kk = 0; kk < 16; kk++) {
      int c = kk * 4 + q;
      bf8 a = *(const bf8*)(smem + 32 * 512 + (mloc * 64 + (c ^ (mloc & 7))) * 8);
      const unsigned short* wb = Wk + ((size_t)(ntb * 16 + kk) * 64 + lane) * 8;
      acc0 = __builtin_amdgcn_mfma_f32_16x16x32_bf16(a, *(const bf8*)(wb), acc0, 0, 0, 0);
      acc1 = __builtin_amdgcn_mfma_f32_16x16x32_bf16(a, *(const bf8*)(wb + GSTRIDE), acc1, 0, 0, 0);
      acc2 = __builtin_amdgcn_mfma_f32_16x16x32_bf16(a, *(const bf8*)(wb + 2 * GSTRIDE), acc2, 0, 0, 0);
      acc3 = __builtin_amdgcn_mfma_f32_16x16x32_bf16(a, *(const bf8*)(wb + 3 * GSTRIDE), acc3, 0, 0, 0);
    }
  }

  // ---- gate pointwise; C/D layout: col = lane&15, row = q*4 + reg ----
  const int rowb = mt * 32 + mh * 16 + q * 4;
  const int u = nt * 32 + nh * 16 + l15;
  float* cst = cbuf[layer];
  const float* bias = layer == 1 ? p.b1 : p.b2;
#pragma unroll
  for (int r = 0; r < 4; r++) {
    int rr = rowb + r;
    float zi = acc0[r], zf = acc1[r], zg = acc2[r], zo = acc3[r];
    if (layer == 0) {
      int xv = p.X[rr * T_ + t];
      const float* tb = p.table + (size_t)xv * G4_;
      const float* cv = p.cvec + (size_t)rr * G4_;
      zi += tb[u]        + cv[u];
      zf += tb[u + 512]  + cv[u + 512];
      zg += tb[u + 1024] + cv[u + 1024];
      zo += tb[u + 1536] + cv[u + 1536];
    } else {
      zi += bias[u]; zf += bias[u + 512]; zg += bias[u + 1024]; zo += bias[u + 1536];
    }
    float cp = cst[(size_t)rr * U_ + u];
    float cn = sigf(zf) * cp + sigf(zi) * tanhf(zg);
    float hn = sigf(zo) * tanhf(cn);
    cst[(size_t)rr * U_ + u] = cn;
    hout[(size_t)rr * U_ + u] = f2bf(hn);
  }
}

__global__ void finalize_kernel(const float* sums, float* out) {
  if (threadIdx.x == 0) {
    float recon = sums[0] * (1.f / ((float)B_ * (float)T_));
    float latent = -0.5f * sums[1] * (1.f / ((float)B_ * (float)LAT_));
    out[0] = recon + latent;
    out[1] = recon;
    out[2] = latent;
  }
}

// ---------------------------------------------------------------------------
extern "C" void kernel_launch(void* const* d_in, const int* in_sizes, int n_in,
                              void* d_out, int out_size, void* d_ws, size_t ws_size,
                              hipStream_t stream) {
  const int*   X       = (const int*)d_in[0];
  const int*   Y       = (const int*)d_in[1];
  const float* C       = (const float*)d_in[2];
  const int*   L       = (const int*)d_in[3];
  const float* eps     = (const float*)d_in[4];
  const float* emb_enc = (const float*)d_in[5];
  const float* emb_dec = (const float*)d_in[6];
  const float* enc_k0  = (const float*)d_in[7];
  const float* enc_rk0 = (const float*)d_in[8];
  const float* enc_b0  = (const float*)d_in[9];
  const float* enc_k1  = (const float*)d_in[10];
  const float* enc_rk1 = (const float*)d_in[11];
  const float* enc_b1  = (const float*)d_in[12];
  const float* enc_k2  = (const float*)d_in[13];
  const float* enc_rk2 = (const float*)d_in[14];
  const float* enc_b2  = (const float*)d_in[15];
  const float* dec_k0  = (const float*)d_in[16];
  const float* dec_rk0 = (const float*)d_in[17];
  const float* dec_b0  = (const float*)d_in[18];
  const float* dec_k1  = (const float*)d_in[19];
  const float* dec_rk1 = (const float*)d_in[20];
  const float* dec_b1  = (const float*)d_in[21];
  const float* dec_k2  = (const float*)d_in[22];
  const float* dec_rk2 = (const float*)d_in[23];
  const float* dec_b2  = (const float*)d_in[24];
  const float* Wm      = (const float*)d_in[25];
  const float* bm      = (const float*)d_in[26];
  const float* Ws      = (const float*)d_in[27];
  const float* bs      = (const float*)d_in[28];
  const float* Wo      = (const float*)d_in[29];
  const float* bo      = (const float*)d_in[30];
  float* out = (float*)d_out;
  (void)in_sizes; (void)n_in; (void)out_size; (void)ws_size;

  char* w = (char*)d_ws;
  size_t o = 0;
  auto take = [&](size_t bytes) -> char* { char* p = w + o; o += (bytes + 255) & ~(size_t)255; return p; };

  // ---- zeroed region (h/c state + accumulators) ----
  unsigned short* hE[3][2]; unsigned short* hD[3][2];
  for (int l = 0; l < 3; l++) for (int pi = 0; pi < 2; pi++) hE[l][pi] = (unsigned short*)take((size_t)B_ * U_ * 2);
  for (int l = 0; l < 3; l++) for (int pi = 0; pi < 2; pi++) hD[l][pi] = (unsigned short*)take((size_t)B_ * U_ * 2);
  float* cE[3]; float* cD[3];
  for (int l = 0; l < 3; l++) cE[l] = (float*)take((size_t)B_ * U_ * 4);
  for (int l = 0; l < 3; l++) cD[l] = (float*)take((size_t)B_ * U_ * 4);
  float* sums = (float*)take(8);  // [0]=ce_sum, [1]=latent_sum
  size_t zero_bytes = o;
  // ---- computed-per-call region ----
  unsigned short* wsw = (unsigned short*)take((size_t)10 * U_ * G4_ * 2);
  float* tabE  = (float*)take((size_t)V_ * G4_ * 4);
  float* tabD  = (float*)take((size_t)V_ * G4_ * 4);
  float* cvecb = (float*)take((size_t)B_ * G4_ * 4);
  float* dvecb = (float*)take((size_t)B_ * G4_ * 4);
  float* zlat  = (float*)take((size_t)B_ * LAT_ * 4);

  hipMemsetAsync(w, 0, zero_bytes, stream);

  SwzParams sp;
  const float* srcs[10] = {enc_rk0, enc_k1, enc_rk1, enc_k2, enc_rk2,
                           dec_rk0, dec_k1, dec_rk1, dec_k2, dec_rk2};
  for (int i = 0; i < 10; i++) sp.src[i] = srcs[i];
  sp.dst = wsw;
  swizzle_kernel<<<1280, 256, 0, stream>>>(sp);
  table_kernel<<<V_, 256, 0, stream>>>(emb_enc, enc_k0, 0, tabE);
  table_kernel<<<V_, 256, 0, stream>>>(emb_dec, dec_k0, 200, tabD);
  cvec_kernel<<<B_, 256, 0, stream>>>(C, enc_k0, enc_b0, cvecb);

  const size_t MS = (size_t)U_ * G4_;  // ushort elems per swizzled matrix

  // ---- encoder wavefront ----
  StepParams ep{};
  ep.Wr0 = wsw + 0 * MS; ep.Wk1 = wsw + 1 * MS; ep.Wr1 = wsw + 2 * MS;
  ep.Wk2 = wsw + 3 * MS; ep.Wr2 = wsw + 4 * MS;
  ep.b1 = enc_b1; ep.b2 = enc_b2;
  ep.table = tabE; ep.cvec = cvecb; ep.X = X;
  ep.h0a = hE[0][0]; ep.h0b = hE[0][1]; ep.h1a = hE[1][0]; ep.h1b = hE[1][1];
  ep.h2a = hE[2][0]; ep.h2b = hE[2][1];
  ep.c0 = cE[0]; ep.c1 = cE[1]; ep.c2 = cE[2];
  for (int s = 0; s < T_ + 2; s++) { ep.s = s; step_kernel<<<384, 256, 0, stream>>>(ep); }

  vae_kernel<<<B_, 256, 0, stream>>>(cE[2], Wm, bm, Ws, bs, eps, zlat, sums + 1);
  dvec_kernel<<<B_, 256, 0, stream>>>(zlat, C, dec_k0, dec_b0, dvecb);

  // ---- decoder wavefront (+ CE stage) ----
  StepParams dp{};
  dp.Wr0 = wsw + 5 * MS; dp.Wk1 = wsw + 6 * MS; dp.Wr1 = wsw + 7 * MS;
  dp.Wk2 = wsw + 8 * MS; dp.Wr2 = wsw + 9 * MS;
  dp.b1 = dec_b1; dp.b2 = dec_b2;
  dp.table = tabD; dp.cvec = dvecb; dp.X = X;
  dp.h0a = hD[0][0]; dp.h0b = hD[0][1]; dp.h1a = hD[1][0]; dp.h1b = hD[1][1];
  dp.h2a = hD[2][0]; dp.h2b = hD[2][1];
  dp.c0 = cD[0]; dp.c1 = cD[1]; dp.c2 = cD[2];
  dp.Wo = Wo; dp.bo = bo; dp.Y = Y; dp.Lb = L; dp.ce_sum = sums + 0;
  for (int s = 0; s < T_ + 3; s++) { dp.s = s; step_kernel<<<392, 256, 0, stream>>>(dp); }

  finalize_kernel<<<1, 64, 0, stream>>>(sums, out);
}

// Round 2
// 9337.705 us; speedup vs baseline: 1.9164x; 1.9164x over previous
//
#include <hip/hip_runtime.h>

#define B_ 256
#define T_ 128
#define V_ 42
#define LAT_ 200
#define U_ 512
#define G4_ 2048
#define NBLK 196

typedef unsigned short ushort_t;
typedef __attribute__((ext_vector_type(8))) short bf8;
typedef __attribute__((ext_vector_type(4))) float f4;

__device__ __forceinline__ float bf2f(ushort_t u) {
  union { unsigned int i; float f; } v; v.i = ((unsigned int)u) << 16; return v.f;
}
__device__ __forceinline__ ushort_t f2bf(float f) {
  union { float f; unsigned int i; } v; v.f = f;
  unsigned int r = v.i + 0x7fffu + ((v.i >> 16) & 1u);
  return (ushort_t)(r >> 16);
}
__device__ __forceinline__ float sigf(float x) { return 1.f / (1.f + __expf(-x)); }

// table[v][j] = sum_n emb[v,n] * k0[roff+n][j]
__global__ __launch_bounds__(256) void table_kernel(const float* emb, const float* k0, int roff, float* table) {
  int v = blockIdx.x, tid = threadIdx.x;
  __shared__ float e[LAT_];
  for (int i = tid; i < LAT_; i += 256) e[i] = emb[v * LAT_ + i];
  __syncthreads();
  for (int j = tid; j < G4_; j += 256) {
    float s = 0.f;
    for (int n = 0; n < LAT_; n++) s += e[n] * k0[(size_t)(roff + n) * G4_ + j];
    table[v * G4_ + j] = s;
  }
}

// ---------------------------------------------------------------------------
// Swizzled-weight layout per matrix: [nt16][kt][lane][8] bf16, where the
// B-fragment for MFMA 16x16x32 at (nt16, kt) is 64 lanes x 16B contiguous:
// n = nt16*16 + (lane&15), k = kt*32 + (lane>>4)*8 + j.
// Mats: 0=encL0ext(KT18) 1=decL0ext(KT26) 2..5=encK1,R1,K2,R2 6..9=dec...
// 10=Wo (3 nt16, KT16, 48 cols padded).
// ---------------------------------------------------------------------------
__device__ __forceinline__ size_t mat_off_u4(int m) {
  if (m == 0) return 0;
  if (m == 1) return 147456;
  if (m < 10) return 360448 + (size_t)(m - 2) * 131072;
  return 1409024;
}

struct SwzSrc {
  const float *enc_rk0, *enc_k0, *enc_b0;
  const float *dec_rk0, *dec_k0, *dec_b0;
  const float *tabE, *tabD;
  const float *encK1, *encR1, *encK2, *encR2;
  const float *decK1, *decR1, *decK2, *decR2;
  const float *Wo;
  ushort_t* dst;
};

__device__ float swz_val(const SwzSrc& s, int mat, int k, int n) {
  switch (mat) {
    case 0: {
      if (k < 512) return s.enc_rk0[(size_t)k * G4_ + n];
      int i = k - 512;
      if (i < 42) return s.tabE[(size_t)i * G4_ + n];
      if (i < 45) return s.enc_k0[(size_t)(200 + i - 42) * G4_ + n];
      if (i == 45) return s.enc_b0[n];
      return 0.f;
    }
    case 1: {
      if (k < 512) return s.dec_rk0[(size_t)k * G4_ + n];
      int i = k - 512;
      if (i < 200) return s.dec_k0[(size_t)i * G4_ + n];
      if (i < 256) return 0.f;
      i -= 256;
      if (i < 42) return s.tabD[(size_t)i * G4_ + n];
      if (i < 45) return s.dec_k0[(size_t)(400 + i - 42) * G4_ + n];
      if (i == 45) return s.dec_b0[n];
      return 0.f;
    }
    case 2: return s.encK1[(size_t)k * G4_ + n];
    case 3: return s.encR1[(size_t)k * G4_ + n];
    case 4: return s.encK2[(size_t)k * G4_ + n];
    case 5: return s.encR2[(size_t)k * G4_ + n];
    case 6: return s.decK1[(size_t)k * G4_ + n];
    case 7: return s.decR1[(size_t)k * G4_ + n];
    case 8: return s.decK2[(size_t)k * G4_ + n];
    case 9: return s.decR2[(size_t)k * G4_ + n];
    default: return (n < V_) ? s.Wo[(size_t)k * V_ + n] : 0.f;
  }
}

__global__ __launch_bounds__(256) void swz_ext_kernel(SwzSrc s) {
  int b = blockIdx.x, tid = threadIdx.x;
  int mat, nt16;
  if (b < 1280) { mat = b >> 7; nt16 = b & 127; } else { mat = 10; nt16 = b - 1280; }
  int ktMax = (mat == 0) ? 18 : (mat == 1) ? 26 : 16;
  int lane = tid & 63, l15 = lane & 15, q = lane >> 4;
  int n = nt16 * 16 + l15;
  uint4* dst = (uint4*)s.dst;
  size_t off = mat_off_u4(mat);
  for (int kt = tid >> 6; kt < ktMax; kt += 4) {
    ushort_t o[8];
    int kb = kt * 32 + q * 8;
#pragma unroll
    for (int j = 0; j < 8; j++) o[j] = f2bf(swz_val(s, mat, kb + j, n));
    dst[off + ((size_t)nt16 * ktMax + kt) * 64 + lane] = *(const uint4*)o;
  }
}

// ---------------------------------------------------------------------------
struct PP {
  const ushort_t* swz;
  ushort_t *he0a, *he0b, *he1a, *he1b, *he2a, *he2b;
  ushort_t *hd0a, *hd0b, *hd1a, *hd1b, *hd2a, *hd2b;
  float* c2g; ushort_t* zf16; float* sums; int* bar; int* gen; float* out;
  const float *enc_b1, *enc_b2, *dec_b1, *dec_b2;
  const float *Wm, *bm, *Ws, *bs, *eps, *C, *bo;
  const int *X, *Y, *Lb;
};

__device__ __forceinline__ void grid_barrier(int* bar, int* gen) {
  __syncthreads();
  if (threadIdx.x == 0) {
    __threadfence();
    int g = __hip_atomic_load(gen, __ATOMIC_RELAXED, __HIP_MEMORY_SCOPE_AGENT);
    if (__hip_atomic_fetch_add(bar, 1, __ATOMIC_ACQ_REL, __HIP_MEMORY_SCOPE_AGENT) == NBLK - 1) {
      __hip_atomic_store(bar, 0, __ATOMIC_RELAXED, __HIP_MEMORY_SCOPE_AGENT);
      __hip_atomic_store(gen, g + 1, __ATOMIC_RELEASE, __HIP_MEMORY_SCOPE_AGENT);
    } else {
      int gg;
      do {
        __builtin_amdgcn_s_sleep(1);
        gg = __hip_atomic_load(gen, __ATOMIC_ACQUIRE, __HIP_MEMORY_SCOPE_AGENT);
      } while (gg == g);
    }
    __threadfence();
  }
  __syncthreads();
}

#define MFMA(a, bfrag, c) __builtin_amdgcn_mfma_f32_16x16x32_bf16((a), (bfrag), (c), 0, 0, 0)

__global__ __launch_bounds__(256, 1) void persist(PP p) {
  __shared__ uint4 wlds4[8192];  // 128KB
  const int b = blockIdx.x, tid = threadIdx.x;
  const int lane = tid & 63, w = tid >> 6, q = lane >> 4, l15 = lane & 15;
  const int role = b < 64 ? 0 : b < 128 ? 1 : b < 192 ? 2 : 3;
  const int idx = b & 63;
  const int ut = idx >> 1, m0 = (idx & 1) * 128;
  const int rw = m0 + w * 32;
  const int u = ut * 16 + l15;
  const uint4* swzU4 = (const uint4*)p.swz;

  ushort_t* hE[3][2] = {{p.he0a, p.he0b}, {p.he1a, p.he1b}, {p.he2a, p.he2b}};
  ushort_t* hD[3][2] = {{p.hd0a, p.hd0b}, {p.hd1a, p.hd1b}, {p.hd2a, p.hd2b}};

  // layer-0 per-lane constants: C rows as bf16 (A-side const region)
  ushort_t cb0[2][3];
  if (role == 0) {
#pragma unroll
    for (int ms = 0; ms < 2; ms++)
#pragma unroll
      for (int j = 0; j < 3; j++) cb0[ms][j] = f2bf(p.C[(rw + ms * 16 + l15) * 3 + j]);
  }

  // CE state
  float ce_local = 0.f;
  float boR0 = 0.f, boR1 = 0.f, boR2 = 0.f;
  int Lr[4] = {0, 0, 0, 0};

  for (int phase = 0; phase < 2; phase++) {
    const bool dec = (phase == 1);
    ushort_t* (*hb)[2] = dec ? hD : hE;

    // ---- mid-phase: VAE (blocks 0..49), uses LDS as scratch before staging ----
    if (dec && b < 50) {
      int lat0 = b * 4;
      int row = tid;
      float m[4], ls[4];
#pragma unroll
      for (int lc = 0; lc < 4; lc++) { m[lc] = p.bm[lat0 + lc]; ls[lc] = p.bs[lat0 + lc]; }
      const float* cr = p.c2g + (size_t)row * U_;
      for (int k = 0; k < U_; k++) {
        float hv = cr[k];
#pragma unroll
        for (int lc = 0; lc < 4; lc++) {
          m[lc] += hv * p.Wm[k * LAT_ + lat0 + lc];
          ls[lc] += hv * p.Ws[k * LAT_ + lat0 + lc];
        }
      }
      float kl = 0.f;
#pragma unroll
      for (int lc = 0; lc < 4; lc++) {
        int lat = lat0 + lc;
        float zz = m[lc] + __expf(0.5f * ls[lc]) * p.eps[row * LAT_ + lat];
        p.zf16[row * 256 + lat] = f2bf(zz);
        kl += 1.f + ls[lc] - m[lc] * m[lc] - __expf(ls[lc]);
      }
      float* red = (float*)wlds4;
      red[tid] = kl; __syncthreads();
      for (int st = 128; st > 0; st >>= 1) { if (tid < st) red[tid] += red[tid + st]; __syncthreads(); }
      if (tid == 0) atomicAdd(p.sums + 1, red[0]);
    }
    __syncthreads();

    // ---- stage weights for this phase into LDS ----
    const int KT = dec ? 26 : 18;          // role-0 extended K tiles
    if (role == 0) {
      int mat = dec ? 1 : 0;
      size_t mo = mat_off_u4(mat);
      for (int g = 0; g < 4; g++) {
        int nt16 = g * 32 + ut;
        size_t src = mo + (size_t)nt16 * KT * 64;
        int dst = g * KT * 64;
        for (int i = tid; i < KT * 64; i += 256) wlds4[dst + i] = swzU4[src + i];
      }
    } else if (role <= 2) {
      int matK = dec ? (role == 1 ? 6 : 8) : (role == 1 ? 2 : 4);
      for (int gm = 0; gm < 2; gm++) {
        size_t mo = mat_off_u4(matK + gm);
        for (int g = 0; g < 4; g++) {
          int nt16 = g * 32 + ut;
          size_t src = mo + (size_t)nt16 * 1024;
          int dst = gm * 4096 + g * 1024;
          for (int i = tid; i < 1024; i += 256) wlds4[dst + i] = swzU4[src + i];
        }
      }
    } else if (dec) {
      size_t mo = mat_off_u4(10);
      for (int i = tid; i < 3072; i += 256) wlds4[i] = swzU4[mo + i];
      int r0c = (b - 192) * 64 + w * 16;
      boR0 = p.bo[l15]; boR1 = p.bo[16 + l15]; boR2 = (l15 < 10) ? p.bo[32 + l15] : 0.f;
#pragma unroll
      for (int r = 0; r < 4; r++) Lr[r] = p.Lb[r0c + q * 4 + r];
    }
    __syncthreads();

    // ---- per-phase register state ----
    float creg[2][4];
#pragma unroll
    for (int ms = 0; ms < 2; ms++)
#pragma unroll
      for (int r = 0; r < 4; r++) creg[ms][r] = 0.f;
    float bias[4] = {0.f, 0.f, 0.f, 0.f};
    if (role == 1 || role == 2) {
      const float* bb = dec ? (role == 1 ? p.dec_b1 : p.dec_b2) : (role == 1 ? p.enc_b1 : p.enc_b2);
#pragma unroll
      for (int g = 0; g < 4; g++) bias[g] = bb[g * 512 + u];
    }

    grid_barrier(p.bar, p.gen);

    // ---- wavefront steps ----
    const int smax = dec ? T_ + 3 : T_ + 2;
    for (int s = 0; s < smax; s++) {
      const int prv = (s & 1) ^ 1, cur = s & 1;
      const int lag = (role <= 2) ? role : 3;
      const int t = s - lag;
      if (t >= 0 && t < T_) {
        if (role == 3) {
          // ======== CE: logits GEMM + online softmax ========
          int r0c = (b - 192) * 64 + w * 16;
          const ushort_t* Ar = hb[2][prv] + (size_t)(r0c + l15) * U_ + q * 8;
          f4 a3[3];
#pragma unroll
          for (int nt = 0; nt < 3; nt++) a3[nt] = (f4){0.f, 0.f, 0.f, 0.f};
#pragma unroll 4
          for (int kt = 0; kt < 16; kt++) {
            bf8 a = *(const bf8*)(Ar + kt * 32);
#pragma unroll
            for (int nt = 0; nt < 3; nt++) {
              bf8 bbf = *(const bf8*)&wlds4[nt * 1024 + kt * 64 + lane];
              a3[nt] = MFMA(a, bbf, a3[nt]);
            }
          }
#pragma unroll
          for (int r = 0; r < 4; r++) {
            int row = r0c + q * 4 + r;
            float v0 = a3[0][r] + boR0;
            float v1 = a3[1][r] + boR1;
            float v2 = (l15 < 10) ? a3[2][r] + boR2 : -3.0e38f;
            float mx = fmaxf(fmaxf(v0, v1), v2);
            mx = fmaxf(mx, __shfl_xor(mx, 1)); mx = fmaxf(mx, __shfl_xor(mx, 2));
            mx = fmaxf(mx, __shfl_xor(mx, 4)); mx = fmaxf(mx, __shfl_xor(mx, 8));
            float se = __expf(v0 - mx) + __expf(v1 - mx) + ((l15 < 10) ? __expf(v2 - mx) : 0.f);
            int yv = p.Y[row * T_ + t];
            float py = (l15 == yv ? v0 : 0.f) + (l15 + 16 == yv ? v1 : 0.f) + (l15 + 32 == yv ? v2 : 0.f);
            se += __shfl_xor(se, 1); se += __shfl_xor(se, 2); se += __shfl_xor(se, 4); se += __shfl_xor(se, 8);
            py += __shfl_xor(py, 1); py += __shfl_xor(py, 2); py += __shfl_xor(py, 4); py += __shfl_xor(py, 8);
            if (l15 == 0 && t < Lr[r]) ce_local += mx + __logf(se) - py;
          }
        } else {
          // ======== LSTM layer step ========
          f4 acc[2][4];
#pragma unroll
          for (int ms = 0; ms < 2; ms++)
#pragma unroll
            for (int g = 0; g < 4; g++) acc[ms][g] = (f4){0.f, 0.f, 0.f, 0.f};

          const ushort_t* hin = hb[role][prv];
          ushort_t* hout = hb[role][cur];
          const ushort_t* Ah0 = hin + (size_t)(rw + l15) * U_ + q * 8;
          const ushort_t* Ah1 = Ah0 + 16 * U_;

          if (role == 0) {
            const int KT64 = KT * 64;
#pragma unroll 4
            for (int kt = 0; kt < 16; kt++) {
              bf8 a0 = *(const bf8*)(Ah0 + kt * 32);
              bf8 a1 = *(const bf8*)(Ah1 + kt * 32);
#pragma unroll
              for (int g = 0; g < 4; g++) {
                bf8 bbf = *(const bf8*)&wlds4[g * KT64 + kt * 64 + lane];
                acc[0][g] = MFMA(a0, bbf, acc[0][g]);
                acc[1][g] = MFMA(a1, bbf, acc[1][g]);
              }
            }
            if (dec) {  // z-region kt 16..23
              const ushort_t* Az0 = p.zf16 + (rw + l15) * 256 + q * 8;
              const ushort_t* Az1 = Az0 + 16 * 256;
#pragma unroll 4
              for (int kz = 0; kz < 8; kz++) {
                bf8 a0 = *(const bf8*)(Az0 + kz * 32);
                bf8 a1 = *(const bf8*)(Az1 + kz * 32);
#pragma unroll
                for (int g = 0; g < 4; g++) {
                  bf8 bbf = *(const bf8*)&wlds4[g * KT64 + (16 + kz) * 64 + lane];
                  acc[0][g] = MFMA(a0, bbf, acc[0][g]);
                  acc[1][g] = MFMA(a1, bbf, acc[1][g]);
                }
              }
            }
            // const region (onehot token, C, 1) kt KT-2..KT-1
            int xv0 = p.X[(rw + l15) * T_ + t];
            int xv1 = p.X[(rw + 16 + l15) * T_ + t];
#pragma unroll
            for (int ktc = 0; ktc < 2; ktc++) {
              union { ushort_t us[8]; bf8 v; } a0u, a1u;
#pragma unroll
              for (int j = 0; j < 8; j++) {
                int id = ktc * 32 + q * 8 + j;
                ushort_t v0 = (id == xv0) ? (ushort_t)0x3F80 : (ushort_t)0;
                ushort_t v1 = (id == xv1) ? (ushort_t)0x3F80 : (ushort_t)0;
                if (id >= 42 && id < 45) { v0 = cb0[0][id - 42]; v1 = cb0[1][id - 42]; }
                if (id == 45) { v0 = 0x3F80; v1 = 0x3F80; }
                a0u.us[j] = v0; a1u.us[j] = v1;
              }
              int kt = KT - 2 + ktc;
#pragma unroll
              for (int g = 0; g < 4; g++) {
                bf8 bbf = *(const bf8*)&wlds4[g * KT64 + kt * 64 + lane];
                acc[0][g] = MFMA(a0u.v, bbf, acc[0][g]);
                acc[1][g] = MFMA(a1u.v, bbf, acc[1][g]);
              }
            }
          } else {
            const ushort_t* xin = hb[role - 1][prv];
            const ushort_t* Ax0 = xin + (size_t)(rw + l15) * U_ + q * 8;
            const ushort_t* Ax1 = Ax0 + 16 * U_;
#pragma unroll 4
            for (int kt = 0; kt < 16; kt++) {
              bf8 a0 = *(const bf8*)(Ax0 + kt * 32);
              bf8 a1 = *(const bf8*)(Ax1 + kt * 32);
#pragma unroll
              for (int g = 0; g < 4; g++) {
                bf8 bbf = *(const bf8*)&wlds4[g * 1024 + kt * 64 + lane];
                acc[0][g] = MFMA(a0, bbf, acc[0][g]);
                acc[1][g] = MFMA(a1, bbf, acc[1][g]);
              }
            }
#pragma unroll 4
            for (int kt = 0; kt < 16; kt++) {
              bf8 a0 = *(const bf8*)(Ah0 + kt * 32);
              bf8 a1 = *(const bf8*)(Ah1 + kt * 32);
#pragma unroll
              for (int g = 0; g < 4; g++) {
                bf8 bbf = *(const bf8*)&wlds4[4096 + g * 1024 + kt * 64 + lane];
                acc[0][g] = MFMA(a0, bbf, acc[0][g]);
                acc[1][g] = MFMA(a1, bbf, acc[1][g]);
              }
            }
          }

          // ---- gate pointwise: row = rw + ms*16 + q*4 + r, unit = u ----
#pragma unroll
          for (int ms = 0; ms < 2; ms++)
#pragma unroll
            for (int r = 0; r < 4; r++) {
              int row = rw + ms * 16 + q * 4 + r;
              float zi = acc[ms][0][r] + bias[0];
              float zf = acc[ms][1][r] + bias[1];
              float zg = acc[ms][2][r] + bias[2];
              float zo = acc[ms][3][r] + bias[3];
              float cp = creg[ms][r];
              float cn = sigf(zf) * cp + sigf(zi) * tanhf(zg);
              float hn = sigf(zo) * tanhf(cn);
              creg[ms][r] = cn;
              hout[(size_t)row * U_ + u] = f2bf(hn);
              if (!dec && role == 2 && t == T_ - 1) p.c2g[(size_t)row * U_ + u] = cn;
            }
        }
      }
      grid_barrier(p.bar, p.gen);
    }
  }

  // ---- CE flush, final reduce ----
  if (role == 3 && l15 == 0) atomicAdd(p.sums + 0, ce_local);
  grid_barrier(p.bar, p.gen);
  if (b == 0 && tid == 0) {
    float recon = p.sums[0] * (1.f / ((float)B_ * (float)T_));
    float latent = -0.5f * p.sums[1] * (1.f / ((float)B_ * (float)LAT_));
    p.out[0] = recon + latent;
    p.out[1] = recon;
    p.out[2] = latent;
  }
}

// ---------------------------------------------------------------------------
extern "C" void kernel_launch(void* const* d_in, const int* in_sizes, int n_in,
                              void* d_out, int out_size, void* d_ws, size_t ws_size,
                              hipStream_t stream) {
  const int*   X       = (const int*)d_in[0];
  const int*   Y       = (const int*)d_in[1];
  const float* C       = (const float*)d_in[2];
  const int*   L       = (const int*)d_in[3];
  const float* eps     = (const float*)d_in[4];
  const float* emb_enc = (const float*)d_in[5];
  const float* emb_dec = (const float*)d_in[6];
  const float* enc_k0  = (const float*)d_in[7];
  const float* enc_rk0 = (const float*)d_in[8];
  const float* enc_b0  = (const float*)d_in[9];
  const float* enc_k1  = (const float*)d_in[10];
  const float* enc_rk1 = (const float*)d_in[11];
  const float* enc_b1  = (const float*)d_in[12];
  const float* enc_k2  = (const float*)d_in[13];
  const float* enc_rk2 = (const float*)d_in[14];
  const float* enc_b2  = (const float*)d_in[15];
  const float* dec_k0  = (const float*)d_in[16];
  const float* dec_rk0 = (const float*)d_in[17];
  const float* dec_b0  = (const float*)d_in[18];
  const float* dec_k1  = (const float*)d_in[19];
  const float* dec_rk1 = (const float*)d_in[20];
  const float* dec_b1  = (const float*)d_in[21];
  const float* dec_k2  = (const float*)d_in[22];
  const float* dec_rk2 = (const float*)d_in[23];
  const float* dec_b2  = (const float*)d_in[24];
  const float* Wm      = (const float*)d_in[25];
  const float* bm      = (const float*)d_in[26];
  const float* Ws      = (const float*)d_in[27];
  const float* bs      = (const float*)d_in[28];
  const float* Wo      = (const float*)d_in[29];
  const float* bo      = (const float*)d_in[30];
  float* out = (float*)d_out;
  (void)in_sizes; (void)n_in; (void)out_size; (void)ws_size;

  char* wsb = (char*)d_ws;
  size_t o = 0;
  auto take = [&](size_t bytes) -> char* { char* p = wsb + o; o += (bytes + 255) & ~(size_t)255; return p; };

  // ---- zeroed region ----
  ushort_t* hE[3][2]; ushort_t* hD[3][2];
  for (int l = 0; l < 3; l++) for (int pi = 0; pi < 2; pi++) hE[l][pi] = (ushort_t*)take((size_t)B_ * U_ * 2);
  for (int l = 0; l < 3; l++) for (int pi = 0; pi < 2; pi++) hD[l][pi] = (ushort_t*)take((size_t)B_ * U_ * 2);
  float* c2g  = (float*)take((size_t)B_ * U_ * 4);
  ushort_t* zf16 = (ushort_t*)take((size_t)B_ * 256 * 2);
  float* sums = (float*)take(8);
  int* bar = (int*)take(4);
  int* gen = (int*)take(4);
  size_t zero_bytes = o;
  // ---- recomputed-per-call region ----
  ushort_t* swz = (ushort_t*)take((size_t)1412096 * 16);
  float* tabE = (float*)take((size_t)V_ * G4_ * 4);
  float* tabD = (float*)take((size_t)V_ * G4_ * 4);

  hipMemsetAsync(wsb, 0, zero_bytes, stream);
  table_kernel<<<V_, 256, 0, stream>>>(emb_enc, enc_k0, 0, tabE);
  table_kernel<<<V_, 256, 0, stream>>>(emb_dec, dec_k0, 200, tabD);

  SwzSrc ss;
  ss.enc_rk0 = enc_rk0; ss.enc_k0 = enc_k0; ss.enc_b0 = enc_b0;
  ss.dec_rk0 = dec_rk0; ss.dec_k0 = dec_k0; ss.dec_b0 = dec_b0;
  ss.tabE = tabE; ss.tabD = tabD;
  ss.encK1 = enc_k1; ss.encR1 = enc_rk1; ss.encK2 = enc_k2; ss.encR2 = enc_rk2;
  ss.decK1 = dec_k1; ss.decR1 = dec_rk1; ss.decK2 = dec_k2; ss.decR2 = dec_rk2;
  ss.Wo = Wo; ss.dst = swz;
  swz_ext_kernel<<<1283, 256, 0, stream>>>(ss);

  PP pp;
  pp.swz = swz;
  pp.he0a = hE[0][0]; pp.he0b = hE[0][1]; pp.he1a = hE[1][0]; pp.he1b = hE[1][1];
  pp.he2a = hE[2][0]; pp.he2b = hE[2][1];
  pp.hd0a = hD[0][0]; pp.hd0b = hD[0][1]; pp.hd1a = hD[1][0]; pp.hd1b = hD[1][1];
  pp.hd2a = hD[2][0]; pp.hd2b = hD[2][1];
  pp.c2g = c2g; pp.zf16 = zf16; pp.sums = sums; pp.bar = bar; pp.gen = gen; pp.out = out;
  pp.enc_b1 = enc_b1; pp.enc_b2 = enc_b2; pp.dec_b1 = dec_b1; pp.dec_b2 = dec_b2;
  pp.Wm = Wm; pp.bm = bm; pp.Ws = Ws; pp.bs = bs; pp.eps = eps; pp.C = C; pp.bo = bo;
  pp.X = X; pp.Y = Y; pp.Lb = L;
  persist<<<NBLK, 256, 0, stream>>>(pp);
}

// Round 3
// 7554.588 us; speedup vs baseline: 2.3688x; 1.2360x over previous
//
#include <hip/hip_runtime.h>

#define B_ 256
#define T_ 128
#define V_ 42
#define LAT_ 200
#define U_ 512
#define G4_ 2048
#define NBLK 196
#define FI(r, m) ((((r) * 2) + (m)) * 32)

typedef unsigned short ushort_t;
typedef __attribute__((ext_vector_type(8))) short bf8;
typedef __attribute__((ext_vector_type(4))) float f4;

__device__ __forceinline__ float bf2f(ushort_t u) {
  union { unsigned int i; float f; } v; v.i = ((unsigned int)u) << 16; return v.f;
}
__device__ __forceinline__ ushort_t f2bf(float f) {
  union { float f; unsigned int i; } v; v.f = f;
  unsigned int r = v.i + 0x7fffu + ((v.i >> 16) & 1u);
  return (ushort_t)(r >> 16);
}
__device__ __forceinline__ float sigf(float x) { return 1.f / (1.f + __expf(-x)); }

// table[v][j] = sum_n emb[v,n] * k0[roff+n][j]
__global__ __launch_bounds__(256) void table_kernel(const float* emb, const float* k0, int roff, float* table) {
  int v = blockIdx.x, tid = threadIdx.x;
  __shared__ float e[LAT_];
  for (int i = tid; i < LAT_; i += 256) e[i] = emb[v * LAT_ + i];
  __syncthreads();
  for (int j = tid; j < G4_; j += 256) {
    float s = 0.f;
    for (int n = 0; n < LAT_; n++) s += e[n] * k0[(size_t)(roff + n) * G4_ + j];
    table[v * G4_ + j] = s;
  }
}

// ---------------------------------------------------------------------------
// Swizzled-weight layout per matrix: [nt16][kt][lane][8] bf16.
// Mats: 0=encL0ext(KT18) 1=decL0ext(KT26) 2..5=encK1,R1,K2,R2 6..9=dec...
// 10=Wo (3 nt16, KT16, 48 cols padded).
// ---------------------------------------------------------------------------
__device__ __forceinline__ size_t mat_off_u4(int m) {
  if (m == 0) return 0;
  if (m == 1) return 147456;
  if (m < 10) return 360448 + (size_t)(m - 2) * 131072;
  return 1409024;
}

struct SwzSrc {
  const float *enc_rk0, *enc_k0, *enc_b0;
  const float *dec_rk0, *dec_k0, *dec_b0;
  const float *tabE, *tabD;
  const float *encK1, *encR1, *encK2, *encR2;
  const float *decK1, *decR1, *decK2, *decR2;
  const float *Wo;
  ushort_t* dst;
};

__device__ float swz_val(const SwzSrc& s, int mat, int k, int n) {
  switch (mat) {
    case 0: {
      if (k < 512) return s.enc_rk0[(size_t)k * G4_ + n];
      int i = k - 512;
      if (i < 42) return s.tabE[(size_t)i * G4_ + n];
      if (i < 45) return s.enc_k0[(size_t)(200 + i - 42) * G4_ + n];
      if (i == 45) return s.enc_b0[n];
      return 0.f;
    }
    case 1: {
      if (k < 512) return s.dec_rk0[(size_t)k * G4_ + n];
      int i = k - 512;
      if (i < 200) return s.dec_k0[(size_t)i * G4_ + n];
      if (i < 256) return 0.f;
      i -= 256;
      if (i < 42) return s.tabD[(size_t)i * G4_ + n];
      if (i < 45) return s.dec_k0[(size_t)(400 + i - 42) * G4_ + n];
      if (i == 45) return s.dec_b0[n];
      return 0.f;
    }
    case 2: return s.encK1[(size_t)k * G4_ + n];
    case 3: return s.encR1[(size_t)k * G4_ + n];
    case 4: return s.encK2[(size_t)k * G4_ + n];
    case 5: return s.encR2[(size_t)k * G4_ + n];
    case 6: return s.decK1[(size_t)k * G4_ + n];
    case 7: return s.decR1[(size_t)k * G4_ + n];
    case 8: return s.decK2[(size_t)k * G4_ + n];
    case 9: return s.decR2[(size_t)k * G4_ + n];
    default: return (n < V_) ? s.Wo[(size_t)k * V_ + n] : 0.f;
  }
}

__global__ __launch_bounds__(256) void swz_ext_kernel(SwzSrc s) {
  int b = blockIdx.x, tid = threadIdx.x;
  int mat, nt16;
  if (b < 1280) { mat = b >> 7; nt16 = b & 127; } else { mat = 10; nt16 = b - 1280; }
  int ktMax = (mat == 0) ? 18 : (mat == 1) ? 26 : 16;
  int lane = tid & 63, l15 = lane & 15, q = lane >> 4;
  int n = nt16 * 16 + l15;
  uint4* dst = (uint4*)s.dst;
  size_t off = mat_off_u4(mat);
  for (int kt = tid >> 6; kt < ktMax; kt += 4) {
    ushort_t o[8];
    int kb = kt * 32 + q * 8;
#pragma unroll
    for (int j = 0; j < 8; j++) o[j] = f2bf(swz_val(s, mat, kb + j, n));
    dst[off + ((size_t)nt16 * ktMax + kt) * 64 + lane] = *(const uint4*)o;
  }
}

// ---------------------------------------------------------------------------
struct PP {
  const ushort_t* swz;
  ushort_t *he0a, *he0b, *he1a, *he1b, *he2a, *he2b;
  ushort_t *hd0a, *hd0b, *hd1a, *hd1b, *hd2a, *hd2b;
  float* c2g; ushort_t* zf16; float* sums; int* bar; int* gen; int* flg; float* out;
  const float *enc_b1, *enc_b2, *dec_b1, *dec_b2;
  const float *Wm, *bm, *Ws, *bs, *eps, *C, *bo;
  const int *X, *Y, *Lb;
};

// Full grid barrier — phase boundaries only (4 uses). All-thread rel/acq fences.
__device__ __forceinline__ void grid_barrier(int* bar, int* gen) {
  __builtin_amdgcn_fence(__ATOMIC_RELEASE, "agent");
  __syncthreads();
  if (threadIdx.x == 0) {
    int g = __hip_atomic_load(gen, __ATOMIC_RELAXED, __HIP_MEMORY_SCOPE_AGENT);
    if (__hip_atomic_fetch_add(bar, 1, __ATOMIC_ACQ_REL, __HIP_MEMORY_SCOPE_AGENT) == NBLK - 1) {
      __hip_atomic_store(bar, 0, __ATOMIC_RELAXED, __HIP_MEMORY_SCOPE_AGENT);
      __hip_atomic_store(gen, g + 1, __ATOMIC_RELEASE, __HIP_MEMORY_SCOPE_AGENT);
    } else {
      int gg;
      do {
        __builtin_amdgcn_s_sleep(1);
        gg = __hip_atomic_load(gen, __ATOMIC_ACQUIRE, __HIP_MEMORY_SCOPE_AGENT);
      } while (gg == g);
    }
  }
  __syncthreads();
  __builtin_amdgcn_fence(__ATOMIC_ACQUIRE, "agent");
}

// Spin until all cnt flags >= target. Relaxed agent loads (sc1: bypass stale L1/L2).
__device__ __forceinline__ void wait_flags(const int* f, int cnt, int target) {
  int lane = threadIdx.x & 63;
  const int* a = f + (lane < cnt ? lane : 0);
  bool bad;
  do {
    int v = __hip_atomic_load(a, __ATOMIC_RELAXED, __HIP_MEMORY_SCOPE_AGENT);
    bad = (lane < cnt) && (v < target);
  } while (__ballot(bad) != 0ull);
}

__device__ __forceinline__ void st_h(ushort_t* p, ushort_t v) {
  __hip_atomic_store(p, v, __ATOMIC_RELAXED, __HIP_MEMORY_SCOPE_AGENT);
}

#define MFMA(a, bfrag, c) __builtin_amdgcn_mfma_f32_16x16x32_bf16((a), (bfrag), (c), 0, 0, 0)

__global__ __launch_bounds__(256, 1) void persist(PP p) {
  __shared__ uint4 wlds4[8192];  // 128KB
  const int b = blockIdx.x, tid = threadIdx.x;
  const int lane = tid & 63, w = tid >> 6, q = lane >> 4, l15 = lane & 15;
  const int role = b < 64 ? 0 : b < 128 ? 1 : b < 192 ? 2 : 3;
  const int idx = b & 63;
  const int ut = idx >> 1, m0 = (idx & 1) * 128;
  const int mi = idx & 1;
  const int rw = m0 + w * 32;
  const int u = ut * 16 + l15;
  const uint4* swzU4 = (const uint4*)p.swz;
  const int cb = b - 192;

  ushort_t* hE[3][2] = {{p.he0a, p.he0b}, {p.he1a, p.he1b}, {p.he2a, p.he2b}};
  ushort_t* hD[3][2] = {{p.hd0a, p.hd0b}, {p.hd1a, p.hd1b}, {p.hd2a, p.hd2b}};

  // layer-0 per-lane constants: C rows as bf16
  ushort_t cb0[2][3];
  if (role == 0) {
#pragma unroll
    for (int ms = 0; ms < 2; ms++)
#pragma unroll
      for (int j = 0; j < 3; j++) cb0[ms][j] = f2bf(p.C[(rw + ms * 16 + l15) * 3 + j]);
  }

  // publish index
  const int pubidx = (role < 3) ? (FI(role, mi) + ut) : (FI(3, cb >> 1) + (cb & 1));

  // CE state
  float ce_local = 0.f;
  float boR0 = 0.f, boR1 = 0.f, boR2 = 0.f;
  int Lr[4] = {0, 0, 0, 0};
  int pub = 0;

  for (int phase = 0; phase < 2; phase++) {
    const bool dec = (phase == 1);
    ushort_t* (*hb)[2] = dec ? hD : hE;

    if (dec) {
      grid_barrier(p.bar, p.gen);  // encoder fully done; c2g visible
      if (b < 50) {
        // ---- VAE (blocks 0..49): z + KL ----
        int lat0 = b * 4;
        int row = tid;
        float m[4], ls[4];
#pragma unroll
        for (int lc = 0; lc < 4; lc++) { m[lc] = p.bm[lat0 + lc]; ls[lc] = p.bs[lat0 + lc]; }
        const float* cr = p.c2g + (size_t)row * U_;
        for (int k = 0; k < U_; k++) {
          float hv = cr[k];
#pragma unroll
          for (int lc = 0; lc < 4; lc++) {
            m[lc] += hv * p.Wm[k * LAT_ + lat0 + lc];
            ls[lc] += hv * p.Ws[k * LAT_ + lat0 + lc];
          }
        }
        float kl = 0.f;
#pragma unroll
        for (int lc = 0; lc < 4; lc++) {
          int lat = lat0 + lc;
          float zz = m[lc] + __expf(0.5f * ls[lc]) * p.eps[row * LAT_ + lat];
          p.zf16[row * 256 + lat] = f2bf(zz);
          kl += 1.f + ls[lc] - m[lc] * m[lc] - __expf(ls[lc]);
        }
        float* red = (float*)wlds4;
        red[tid] = kl; __syncthreads();
        for (int st = 128; st > 0; st >>= 1) { if (tid < st) red[tid] += red[tid + st]; __syncthreads(); }
        if (tid == 0) atomicAdd(p.sums + 1, red[0]);
      }
      __syncthreads();
    }

    // ---- stage weights for this phase into LDS ----
    const int KT = dec ? 26 : 18;
    if (role == 0) {
      int mat = dec ? 1 : 0;
      size_t mo = mat_off_u4(mat);
      for (int g = 0; g < 4; g++) {
        int nt16 = g * 32 + ut;
        size_t src = mo + (size_t)nt16 * KT * 64;
        int dst = g * KT * 64;
        for (int i = tid; i < KT * 64; i += 256) wlds4[dst + i] = swzU4[src + i];
      }
    } else if (role <= 2) {
      int matK = dec ? (role == 1 ? 6 : 8) : (role == 1 ? 2 : 4);
      for (int gm = 0; gm < 2; gm++) {
        size_t mo = mat_off_u4(matK + gm);
        for (int g = 0; g < 4; g++) {
          int nt16 = g * 32 + ut;
          size_t src = mo + (size_t)nt16 * 1024;
          int dst = gm * 4096 + g * 1024;
          for (int i = tid; i < 1024; i += 256) wlds4[dst + i] = swzU4[src + i];
        }
      }
    } else if (dec) {
      size_t mo = mat_off_u4(10);
      for (int i = tid; i < 3072; i += 256) wlds4[i] = swzU4[mo + i];
      int r0c = cb * 64 + w * 16;
      boR0 = p.bo[l15]; boR1 = p.bo[16 + l15]; boR2 = (l15 < 10) ? p.bo[32 + l15] : 0.f;
#pragma unroll
      for (int r = 0; r < 4; r++) Lr[r] = p.Lb[r0c + q * 4 + r];
    }
    __syncthreads();

    // ---- per-phase register state ----
    float creg[2][4];
#pragma unroll
    for (int ms = 0; ms < 2; ms++)
#pragma unroll
      for (int r = 0; r < 4; r++) creg[ms][r] = 0.f;
    float bias[4] = {0.f, 0.f, 0.f, 0.f};
    if (role == 1 || role == 2) {
      const float* bb = dec ? (role == 1 ? p.dec_b1 : p.dec_b2) : (role == 1 ? p.enc_b1 : p.enc_b2);
#pragma unroll
      for (int g = 0; g < 4; g++) bias[g] = bb[g * 512 + u];
    }

    // ---- per-wave wait-set for this phase ----
    const int* myp = nullptr; int myc = 0;
    if (role == 0) {
      if (w == 0) { myp = p.flg + FI(0, mi); myc = 32; }
      else if (w == 1) { myp = p.flg + FI(1, mi); myc = 32; }
    } else if (role == 1) {
      if (w == 0) { myp = p.flg + FI(0, mi); myc = 32; }
      else if (w == 1) { myp = p.flg + FI(1, mi); myc = 32; }
      else if (w == 2) { myp = p.flg + FI(2, mi); myc = 32; }
    } else if (role == 2) {
      if (w == 0) { myp = p.flg + FI(1, mi); myc = 32; }
      else if (w == 1) { myp = p.flg + FI(2, mi); myc = 32; }
      else if (w == 2 && dec) { myp = p.flg + FI(3, mi); myc = 2; }
    } else {
      if (w == 0 && dec) { myp = p.flg + FI(2, cb >> 1); myc = 32; }
    }

    grid_barrier(p.bar, p.gen);  // phase aligned; zf16/weights visible

    // ---- wavefront steps (flag-synced) ----
    const int smax = dec ? T_ + 3 : T_ + 2;
    for (int s = 0; s < smax; s++) {
      pub++;
      if (myc) wait_flags(myp, myc, pub - 1);
      __builtin_amdgcn_fence(__ATOMIC_ACQUIRE, "agent");
      __syncthreads();

      const int prv = (s & 1) ^ 1, cur = s & 1;
      const int lag = (role <= 2) ? role : 3;
      const int t = s - lag;
      if (t >= 0 && t < T_) {
        if (role == 3) {
          // ======== CE: logits GEMM + online softmax ========
          int r0c = cb * 64 + w * 16;
          const ushort_t* Ar = hb[2][prv] + (size_t)(r0c + l15) * U_ + q * 8;
          f4 a3[3];
#pragma unroll
          for (int nt = 0; nt < 3; nt++) a3[nt] = (f4){0.f, 0.f, 0.f, 0.f};
#pragma unroll 4
          for (int kt = 0; kt < 16; kt++) {
            bf8 a = *(const bf8*)(Ar + kt * 32);
#pragma unroll
            for (int nt = 0; nt < 3; nt++) {
              bf8 bbf = *(const bf8*)&wlds4[nt * 1024 + kt * 64 + lane];
              a3[nt] = MFMA(a, bbf, a3[nt]);
            }
          }
#pragma unroll
          for (int r = 0; r < 4; r++) {
            int row = r0c + q * 4 + r;
            float v0 = a3[0][r] + boR0;
            float v1 = a3[1][r] + boR1;
            float v2 = (l15 < 10) ? a3[2][r] + boR2 : -3.0e38f;
            float mx = fmaxf(fmaxf(v0, v1), v2);
            mx = fmaxf(mx, __shfl_xor(mx, 1)); mx = fmaxf(mx, __shfl_xor(mx, 2));
            mx = fmaxf(mx, __shfl_xor(mx, 4)); mx = fmaxf(mx, __shfl_xor(mx, 8));
            float se = __expf(v0 - mx) + __expf(v1 - mx) + ((l15 < 10) ? __expf(v2 - mx) : 0.f);
            int yv = p.Y[row * T_ + t];
            float py = (l15 == yv ? v0 : 0.f) + (l15 + 16 == yv ? v1 : 0.f) + (l15 + 32 == yv ? v2 : 0.f);
            se += __shfl_xor(se, 1); se += __shfl_xor(se, 2); se += __shfl_xor(se, 4); se += __shfl_xor(se, 8);
            py += __shfl_xor(py, 1); py += __shfl_xor(py, 2); py += __shfl_xor(py, 4); py += __shfl_xor(py, 8);
            if (l15 == 0 && t < Lr[r]) ce_local += mx + __logf(se) - py;
          }
        } else {
          // ======== LSTM layer step ========
          f4 acc[2][4];
#pragma unroll
          for (int ms = 0; ms < 2; ms++)
#pragma unroll
            for (int g = 0; g < 4; g++) acc[ms][g] = (f4){0.f, 0.f, 0.f, 0.f};

          const ushort_t* hin = hb[role][prv];
          ushort_t* hout = hb[role][cur];
          const ushort_t* Ah0 = hin + (size_t)(rw + l15) * U_ + q * 8;
          const ushort_t* Ah1 = Ah0 + 16 * U_;

          if (role == 0) {
            const int KT64 = KT * 64;
#pragma unroll 4
            for (int kt = 0; kt < 16; kt++) {
              bf8 a0 = *(const bf8*)(Ah0 + kt * 32);
              bf8 a1 = *(const bf8*)(Ah1 + kt * 32);
#pragma unroll
              for (int g = 0; g < 4; g++) {
                bf8 bbf = *(const bf8*)&wlds4[g * KT64 + kt * 64 + lane];
                acc[0][g] = MFMA(a0, bbf, acc[0][g]);
                acc[1][g] = MFMA(a1, bbf, acc[1][g]);
              }
            }
            if (dec) {  // z-region kt 16..23
              const ushort_t* Az0 = p.zf16 + (rw + l15) * 256 + q * 8;
              const ushort_t* Az1 = Az0 + 16 * 256;
#pragma unroll 4
              for (int kz = 0; kz < 8; kz++) {
                bf8 a0 = *(const bf8*)(Az0 + kz * 32);
                bf8 a1 = *(const bf8*)(Az1 + kz * 32);
#pragma unroll
                for (int g = 0; g < 4; g++) {
                  bf8 bbf = *(const bf8*)&wlds4[g * KT64 + (16 + kz) * 64 + lane];
                  acc[0][g] = MFMA(a0, bbf, acc[0][g]);
                  acc[1][g] = MFMA(a1, bbf, acc[1][g]);
                }
              }
            }
            // const region (onehot token, C, 1)
            int xv0 = p.X[(rw + l15) * T_ + t];
            int xv1 = p.X[(rw + 16 + l15) * T_ + t];
#pragma unroll
            for (int ktc = 0; ktc < 2; ktc++) {
              union { ushort_t us[8]; bf8 v; } a0u, a1u;
#pragma unroll
              for (int j = 0; j < 8; j++) {
                int id = ktc * 32 + q * 8 + j;
                ushort_t v0 = (id == xv0) ? (ushort_t)0x3F80 : (ushort_t)0;
                ushort_t v1 = (id == xv1) ? (ushort_t)0x3F80 : (ushort_t)0;
                if (id >= 42 && id < 45) { v0 = cb0[0][id - 42]; v1 = cb0[1][id - 42]; }
                if (id == 45) { v0 = 0x3F80; v1 = 0x3F80; }
                a0u.us[j] = v0; a1u.us[j] = v1;
              }
              int kt = KT - 2 + ktc;
#pragma unroll
              for (int g = 0; g < 4; g++) {
                bf8 bbf = *(const bf8*)&wlds4[g * KT64 + kt * 64 + lane];
                acc[0][g] = MFMA(a0u.v, bbf, acc[0][g]);
                acc[1][g] = MFMA(a1u.v, bbf, acc[1][g]);
              }
            }
          } else {
            const ushort_t* xin = hb[role - 1][prv];
            const ushort_t* Ax0 = xin + (size_t)(rw + l15) * U_ + q * 8;
            const ushort_t* Ax1 = Ax0 + 16 * U_;
#pragma unroll 4
            for (int kt = 0; kt < 16; kt++) {
              bf8 a0 = *(const bf8*)(Ax0 + kt * 32);
              bf8 a1 = *(const bf8*)(Ax1 + kt * 32);
#pragma unroll
              for (int g = 0; g < 4; g++) {
                bf8 bbf = *(const bf8*)&wlds4[g * 1024 + kt * 64 + lane];
                acc[0][g] = MFMA(a0, bbf, acc[0][g]);
                acc[1][g] = MFMA(a1, bbf, acc[1][g]);
              }
            }
#pragma unroll 4
            for (int kt = 0; kt < 16; kt++) {
              bf8 a0 = *(const bf8*)(Ah0 + kt * 32);
              bf8 a1 = *(const bf8*)(Ah1 + kt * 32);
#pragma unroll
              for (int g = 0; g < 4; g++) {
                bf8 bbf = *(const bf8*)&wlds4[4096 + g * 1024 + kt * 64 + lane];
                acc[0][g] = MFMA(a0, bbf, acc[0][g]);
                acc[1][g] = MFMA(a1, bbf, acc[1][g]);
              }
            }
          }

          // ---- gate pointwise ----
#pragma unroll
          for (int ms = 0; ms < 2; ms++)
#pragma unroll
            for (int r = 0; r < 4; r++) {
              int row = rw + ms * 16 + q * 4 + r;
              float zi = acc[ms][0][r] + bias[0];
              float zf = acc[ms][1][r] + bias[1];
              float zg = acc[ms][2][r] + bias[2];
              float zo = acc[ms][3][r] + bias[3];
              float cp = creg[ms][r];
              float cn = sigf(zf) * cp + sigf(zi) * tanhf(zg);
              float hn = sigf(zo) * tanhf(cn);
              creg[ms][r] = cn;
              st_h(&hout[(size_t)row * U_ + u], f2bf(hn));
              if (!dec && role == 2 && t == T_ - 1) p.c2g[(size_t)row * U_ + u] = cn;
            }
        }
      }
      __builtin_amdgcn_fence(__ATOMIC_RELEASE, "agent");
      __syncthreads();
      if (tid == 0) __hip_atomic_store(p.flg + pubidx, pub, __ATOMIC_RELAXED, __HIP_MEMORY_SCOPE_AGENT);
    }
  }

  // ---- CE flush, final reduce ----
  if (role == 3 && l15 == 0) atomicAdd(p.sums + 0, ce_local);
  grid_barrier(p.bar, p.gen);
  if (b == 0 && tid == 0) {
    float recon = p.sums[0] * (1.f / ((float)B_ * (float)T_));
    float latent = -0.5f * p.sums[1] * (1.f / ((float)B_ * (float)LAT_));
    p.out[0] = recon + latent;
    p.out[1] = recon;
    p.out[2] = latent;
  }
}

// ---------------------------------------------------------------------------
extern "C" void kernel_launch(void* const* d_in, const int* in_sizes, int n_in,
                              void* d_out, int out_size, void* d_ws, size_t ws_size,
                              hipStream_t stream) {
  const int*   X       = (const int*)d_in[0];
  const int*   Y       = (const int*)d_in[1];
  const float* C       = (const float*)d_in[2];
  const int*   L       = (const int*)d_in[3];
  const float* eps     = (const float*)d_in[4];
  const float* emb_enc = (const float*)d_in[5];
  const float* emb_dec = (const float*)d_in[6];
  const float* enc_k0  = (const float*)d_in[7];
  const float* enc_rk0 = (const float*)d_in[8];
  const float* enc_b0  = (const float*)d_in[9];
  const float* enc_k1  = (const float*)d_in[10];
  const float* enc_rk1 = (const float*)d_in[11];
  const float* enc_b1  = (const float*)d_in[12];
  const float* enc_k2  = (const float*)d_in[13];
  const float* enc_rk2 = (const float*)d_in[14];
  const float* enc_b2  = (const float*)d_in[15];
  const float* dec_k0  = (const float*)d_in[16];
  const float* dec_rk0 = (const float*)d_in[17];
  const float* dec_b0  = (const float*)d_in[18];
  const float* dec_k1  = (const float*)d_in[19];
  const float* dec_rk1 = (const float*)d_in[20];
  const float* dec_b1  = (const float*)d_in[21];
  const float* dec_k2  = (const float*)d_in[22];
  const float* dec_rk2 = (const float*)d_in[23];
  const float* dec_b2  = (const float*)d_in[24];
  const float* Wm      = (const float*)d_in[25];
  const float* bm      = (const float*)d_in[26];
  const float* Ws      = (const float*)d_in[27];
  const float* bs      = (const float*)d_in[28];
  const float* Wo      = (const float*)d_in[29];
  const float* bo      = (const float*)d_in[30];
  float* out = (float*)d_out;
  (void)in_sizes; (void)n_in; (void)out_size; (void)ws_size;

  char* wsb = (char*)d_ws;
  size_t o = 0;
  auto take = [&](size_t bytes) -> char* { char* p = wsb + o; o += (bytes + 255) & ~(size_t)255; return p; };

  // ---- zeroed region ----
  ushort_t* hE[3][2]; ushort_t* hD[3][2];
  for (int l = 0; l < 3; l++) for (int pi = 0; pi < 2; pi++) hE[l][pi] = (ushort_t*)take((size_t)B_ * U_ * 2);
  for (int l = 0; l < 3; l++) for (int pi = 0; pi < 2; pi++) hD[l][pi] = (ushort_t*)take((size_t)B_ * U_ * 2);
  float* c2g  = (float*)take((size_t)B_ * U_ * 4);
  ushort_t* zf16 = (ushort_t*)take((size_t)B_ * 256 * 2);
  float* sums = (float*)take(8);
  int* bar = (int*)take(4);
  int* gen = (int*)take(4);
  int* flg = (int*)take(4 * 2 * 32 * 4);
  size_t zero_bytes = o;
  // ---- recomputed-per-call region ----
  ushort_t* swz = (ushort_t*)take((size_t)1412096 * 16);
  float* tabE = (float*)take((size_t)V_ * G4_ * 4);
  float* tabD = (float*)take((size_t)V_ * G4_ * 4);

  hipMemsetAsync(wsb, 0, zero_bytes, stream);
  table_kernel<<<V_, 256, 0, stream>>>(emb_enc, enc_k0, 0, tabE);
  table_kernel<<<V_, 256, 0, stream>>>(emb_dec, dec_k0, 200, tabD);

  SwzSrc ss;
  ss.enc_rk0 = enc_rk0; ss.enc_k0 = enc_k0; ss.enc_b0 = enc_b0;
  ss.dec_rk0 = dec_rk0; ss.dec_k0 = dec_k0; ss.dec_b0 = dec_b0;
  ss.tabE = tabE; ss.tabD = tabD;
  ss.encK1 = enc_k1; ss.encR1 = enc_rk1; ss.encK2 = enc_k2; ss.encR2 = enc_rk2;
  ss.decK1 = dec_k1; ss.decR1 = dec_rk1; ss.decK2 = dec_k2; ss.decR2 = dec_rk2;
  ss.Wo = Wo; ss.dst = swz;
  swz_ext_kernel<<<1283, 256, 0, stream>>>(ss);

  PP pp;
  pp.swz = swz;
  pp.he0a = hE[0][0]; pp.he0b = hE[0][1]; pp.he1a = hE[1][0]; pp.he1b = hE[1][1];
  pp.he2a = hE[2][0]; pp.he2b = hE[2][1];
  pp.hd0a = hD[0][0]; pp.hd0b = hD[0][1]; pp.hd1a = hD[1][0]; pp.hd1b = hD[1][1];
  pp.hd2a = hD[2][0]; pp.hd2b = hD[2][1];
  pp.c2g = c2g; pp.zf16 = zf16; pp.sums = sums; pp.bar = bar; pp.gen = gen; pp.flg = flg; pp.out = out;
  pp.enc_b1 = enc_b1; pp.enc_b2 = enc_b2; pp.dec_b1 = dec_b1; pp.dec_b2 = dec_b2;
  pp.Wm = Wm; pp.bm = bm; pp.Ws = Ws; pp.bs = bs; pp.eps = eps; pp.C = C; pp.bo = bo;
  pp.X = X; pp.Y = Y; pp.Lb = L;
  persist<<<NBLK, 256, 0, stream>>>(pp);
}

// Round 4
// 5499.617 us; speedup vs baseline: 3.2539x; 1.3737x over previous
//
#include <hip/hip_runtime.h>

#define B_ 256
#define T_ 128
#define V_ 42
#define LAT_ 200
#define U_ 512
#define G4_ 2048
#define NBLK 196
#define FI(r, m) ((((r) * 2) + (m)) * 32)

typedef unsigned short ushort_t;
typedef __attribute__((ext_vector_type(8))) short bf8;
typedef __attribute__((ext_vector_type(4))) float f4;

__device__ __forceinline__ float bf2f(ushort_t u) {
  union { unsigned int i; float f; } v; v.i = ((unsigned int)u) << 16; return v.f;
}
__device__ __forceinline__ ushort_t f2bf(float f) {
  union { float f; unsigned int i; } v; v.f = f;
  unsigned int r = v.i + 0x7fffu + ((v.i >> 16) & 1u);
  return (ushort_t)(r >> 16);
}
__device__ __forceinline__ float sigf(float x) { return 1.f / (1.f + __expf(-x)); }
// NaN-safe fast tanh: x=+inf -> 1, x=-inf -> -1
__device__ __forceinline__ float tanhfast(float x) {
  float e = __expf(2.f * x);
  return 1.f - 2.f / (e + 1.f);
}

// ---- write-through (MALL-coherent) stores + explicit store-ACK wait ----
__device__ __forceinline__ void st_wt_b16(void* p, ushort_t v) {
  unsigned int vv = v;
  asm volatile("global_store_short %0, %1, off sc0 sc1" :: "v"(p), "v"(vv) : "memory");
}
__device__ __forceinline__ void st_wt_b32(void* p, unsigned int v) {
  asm volatile("global_store_dword %0, %1, off sc0 sc1" :: "v"(p), "v"(v) : "memory");
}
__device__ __forceinline__ void wait_vm0() {
  asm volatile("s_waitcnt vmcnt(0)" ::: "memory");
}

// table[v][j] = sum_n emb[v,n] * k0[roff+n][j]
__global__ __launch_bounds__(256) void table_kernel(const float* emb, const float* k0, int roff, float* table) {
  int v = blockIdx.x, tid = threadIdx.x;
  __shared__ float e[LAT_];
  for (int i = tid; i < LAT_; i += 256) e[i] = emb[v * LAT_ + i];
  __syncthreads();
  for (int j = tid; j < G4_; j += 256) {
    float s = 0.f;
    for (int n = 0; n < LAT_; n++) s += e[n] * k0[(size_t)(roff + n) * G4_ + j];
    table[v * G4_ + j] = s;
  }
}

// ---------------------------------------------------------------------------
// Swizzled-weight layout per matrix: [nt16][kt][lane][8] bf16.
// Mats: 0=encL0ext(KT18) 1=decL0ext(KT26) 2..5=encK1,R1,K2,R2 6..9=dec...
// 10=Wo (3 nt16, KT16, 48 cols padded).
// ---------------------------------------------------------------------------
__device__ __forceinline__ size_t mat_off_u4(int m) {
  if (m == 0) return 0;
  if (m == 1) return 147456;
  if (m < 10) return 360448 + (size_t)(m - 2) * 131072;
  return 1409024;
}

struct SwzSrc {
  const float *enc_rk0, *enc_k0, *enc_b0;
  const float *dec_rk0, *dec_k0, *dec_b0;
  const float *tabE, *tabD;
  const float *encK1, *encR1, *encK2, *encR2;
  const float *decK1, *decR1, *decK2, *decR2;
  const float *Wo;
  ushort_t* dst;
};

__device__ float swz_val(const SwzSrc& s, int mat, int k, int n) {
  switch (mat) {
    case 0: {
      if (k < 512) return s.enc_rk0[(size_t)k * G4_ + n];
      int i = k - 512;
      if (i < 42) return s.tabE[(size_t)i * G4_ + n];
      if (i < 45) return s.enc_k0[(size_t)(200 + i - 42) * G4_ + n];
      if (i == 45) return s.enc_b0[n];
      return 0.f;
    }
    case 1: {
      if (k < 512) return s.dec_rk0[(size_t)k * G4_ + n];
      int i = k - 512;
      if (i < 200) return s.dec_k0[(size_t)i * G4_ + n];
      if (i < 256) return 0.f;
      i -= 256;
      if (i < 42) return s.tabD[(size_t)i * G4_ + n];
      if (i < 45) return s.dec_k0[(size_t)(400 + i - 42) * G4_ + n];
      if (i == 45) return s.dec_b0[n];
      return 0.f;
    }
    case 2: return s.encK1[(size_t)k * G4_ + n];
    case 3: return s.encR1[(size_t)k * G4_ + n];
    case 4: return s.encK2[(size_t)k * G4_ + n];
    case 5: return s.encR2[(size_t)k * G4_ + n];
    case 6: return s.decK1[(size_t)k * G4_ + n];
    case 7: return s.decR1[(size_t)k * G4_ + n];
    case 8: return s.decK2[(size_t)k * G4_ + n];
    case 9: return s.decR2[(size_t)k * G4_ + n];
    default: return (n < V_) ? s.Wo[(size_t)k * V_ + n] : 0.f;
  }
}

__global__ __launch_bounds__(256) void swz_ext_kernel(SwzSrc s) {
  int b = blockIdx.x, tid = threadIdx.x;
  int mat, nt16;
  if (b < 1280) { mat = b >> 7; nt16 = b & 127; } else { mat = 10; nt16 = b - 1280; }
  int ktMax = (mat == 0) ? 18 : (mat == 1) ? 26 : 16;
  int lane = tid & 63, l15 = lane & 15, q = lane >> 4;
  int n = nt16 * 16 + l15;
  uint4* dst = (uint4*)s.dst;
  size_t off = mat_off_u4(mat);
  for (int kt = tid >> 6; kt < ktMax; kt += 4) {
    ushort_t o[8];
    int kb = kt * 32 + q * 8;
#pragma unroll
    for (int j = 0; j < 8; j++) o[j] = f2bf(swz_val(s, mat, kb + j, n));
    dst[off + ((size_t)nt16 * ktMax + kt) * 64 + lane] = *(const uint4*)o;
  }
}

// ---------------------------------------------------------------------------
struct PP {
  const ushort_t* swz;
  ushort_t *he0a, *he0b, *he1a, *he1b, *he2a, *he2b;
  ushort_t *hd0a, *hd0b, *hd1a, *hd1b, *hd2a, *hd2b;
  float* c2g; ushort_t* zf16; float* sums; int* bar; int* gen; int* flg; float* out;
  const float *enc_b1, *enc_b2, *dec_b1, *dec_b2;
  const float *Wm, *bm, *Ws, *bs, *eps, *C, *bo;
  const int *X, *Y, *Lb;
};

// Full grid barrier — phase boundaries only. All-thread rel/acq fences.
__device__ __forceinline__ void grid_barrier(int* bar, int* gen) {
  __builtin_amdgcn_fence(__ATOMIC_RELEASE, "agent");
  __syncthreads();
  if (threadIdx.x == 0) {
    int g = __hip_atomic_load(gen, __ATOMIC_RELAXED, __HIP_MEMORY_SCOPE_AGENT);
    if (__hip_atomic_fetch_add(bar, 1, __ATOMIC_ACQ_REL, __HIP_MEMORY_SCOPE_AGENT) == NBLK - 1) {
      __hip_atomic_store(bar, 0, __ATOMIC_RELAXED, __HIP_MEMORY_SCOPE_AGENT);
      __hip_atomic_store(gen, g + 1, __ATOMIC_RELEASE, __HIP_MEMORY_SCOPE_AGENT);
    } else {
      int gg;
      do {
        __builtin_amdgcn_s_sleep(1);
        gg = __hip_atomic_load(gen, __ATOMIC_ACQUIRE, __HIP_MEMORY_SCOPE_AGENT);
      } while (gg == g);
    }
  }
  __syncthreads();
  __builtin_amdgcn_fence(__ATOMIC_ACQUIRE, "agent");
}

// Spin until all cnt flags >= target (relaxed agent loads — observed coherent in R3).
__device__ __forceinline__ void wait_flags(const int* f, int cnt, int target) {
  int lane = threadIdx.x & 63;
  const int* a = f + (lane < cnt ? lane : 0);
  bool bad;
  do {
    int v = __hip_atomic_load(a, __ATOMIC_RELAXED, __HIP_MEMORY_SCOPE_AGENT);
    bad = (lane < cnt) && (v < target);
  } while (__ballot(bad) != 0ull);
}

#define MFMA(a, bfrag, c) __builtin_amdgcn_mfma_f32_16x16x32_bf16((a), (bfrag), (c), 0, 0, 0)

__global__ __launch_bounds__(256, 1) void persist(PP p) {
  __shared__ uint4 wlds4[8192];  // 128KB: weights + token caches
  const int b = blockIdx.x, tid = threadIdx.x;
  const int lane = tid & 63, w = tid >> 6, q = lane >> 4, l15 = lane & 15;
  const int role = b < 64 ? 0 : b < 128 ? 1 : b < 192 ? 2 : 3;
  const int idx = b & 63;
  const int ut = idx >> 1, m0 = (idx & 1) * 128;
  const int mi = idx & 1;
  const int rw = m0 + w * 32;
  const int u = ut * 16 + l15;
  const uint4* swzU4 = (const uint4*)p.swz;
  const int cb = b - 192;

  unsigned char* tok = (unsigned char*)wlds4 + 106496;  // role0 X cache [128][133]
  unsigned char* ytok = (unsigned char*)wlds4 + 49152;  // CE Y cache [64][133]

  ushort_t* hE[3][2] = {{p.he0a, p.he0b}, {p.he1a, p.he1b}, {p.he2a, p.he2b}};
  ushort_t* hD[3][2] = {{p.hd0a, p.hd0b}, {p.hd1a, p.hd1b}, {p.hd2a, p.hd2b}};

  // layer-0 per-lane constants: C rows as bf16
  ushort_t cb0[2][3];
  if (role == 0) {
#pragma unroll
    for (int ms = 0; ms < 2; ms++)
#pragma unroll
      for (int j = 0; j < 3; j++) cb0[ms][j] = f2bf(p.C[(rw + ms * 16 + l15) * 3 + j]);
  }

  const int pubidx = (role < 3) ? (FI(role, mi) + ut) : (FI(3, cb >> 1) + (cb & 1));

  float ce_local = 0.f;
  float boR0 = 0.f, boR1 = 0.f, boR2 = 0.f;
  int Lr[4] = {0, 0, 0, 0};
  int pub = 0;

  for (int phase = 0; phase < 2; phase++) {
    const bool dec = (phase == 1);
    ushort_t* (*hb)[2] = dec ? hD : hE;

    if (dec) {
      grid_barrier(p.bar, p.gen);  // encoder fully done; c2g visible
      if (b < 50) {
        // ---- VAE (blocks 0..49): z + KL ----
        int lat0 = b * 4;
        int row = tid;
        float m[4], ls[4];
#pragma unroll
        for (int lc = 0; lc < 4; lc++) { m[lc] = p.bm[lat0 + lc]; ls[lc] = p.bs[lat0 + lc]; }
        const float* cr = p.c2g + (size_t)row * U_;
        for (int k = 0; k < U_; k++) {
          float hv = cr[k];
#pragma unroll
          for (int lc = 0; lc < 4; lc++) {
            m[lc] += hv * p.Wm[k * LAT_ + lat0 + lc];
            ls[lc] += hv * p.Ws[k * LAT_ + lat0 + lc];
          }
        }
        float kl = 0.f;
#pragma unroll
        for (int lc = 0; lc < 4; lc++) {
          int lat = lat0 + lc;
          float zz = m[lc] + __expf(0.5f * ls[lc]) * p.eps[row * LAT_ + lat];
          p.zf16[row * 256 + lat] = f2bf(zz);
          kl += 1.f + ls[lc] - m[lc] * m[lc] - __expf(ls[lc]);
        }
        float* red = (float*)wlds4;
        red[tid] = kl; __syncthreads();
        for (int st = 128; st > 0; st >>= 1) { if (tid < st) red[tid] += red[tid + st]; __syncthreads(); }
        if (tid == 0) atomicAdd(p.sums + 1, red[0]);
      }
      __syncthreads();
    }

    // ---- stage weights (+ token caches) for this phase into LDS ----
    const int KT = dec ? 26 : 18;
    if (role == 0) {
      int mat = dec ? 1 : 0;
      size_t mo = mat_off_u4(mat);
      for (int g = 0; g < 4; g++) {
        int nt16 = g * 32 + ut;
        size_t src = mo + (size_t)nt16 * KT * 64;
        int dst = g * KT * 64;
        for (int i = tid; i < KT * 64; i += 256) wlds4[dst + i] = swzU4[src + i];
      }
      if (!dec) {  // X token cache (persists through both phases)
        for (int i = tid; i < 128 * T_; i += 256) {
          int r = i >> 7, t = i & 127;
          tok[r * 133 + t] = (unsigned char)p.X[(size_t)(m0 + r) * T_ + t];
        }
      }
    } else if (role <= 2) {
      int matK = dec ? (role == 1 ? 6 : 8) : (role == 1 ? 2 : 4);
      for (int gm = 0; gm < 2; gm++) {
        size_t mo = mat_off_u4(matK + gm);
        for (int g = 0; g < 4; g++) {
          int nt16 = g * 32 + ut;
          size_t src = mo + (size_t)nt16 * 1024;
          int dst = gm * 4096 + g * 1024;
          for (int i = tid; i < 1024; i += 256) wlds4[dst + i] = swzU4[src + i];
        }
      }
    } else if (dec) {
      size_t mo = mat_off_u4(10);
      for (int i = tid; i < 3072; i += 256) wlds4[i] = swzU4[mo + i];
      for (int i = tid; i < 64 * T_; i += 256) {
        int r = i >> 7, t = i & 127;
        ytok[r * 133 + t] = (unsigned char)p.Y[(size_t)(cb * 64 + r) * T_ + t];
      }
      int r0c = cb * 64 + w * 16;
      boR0 = p.bo[l15]; boR1 = p.bo[16 + l15]; boR2 = (l15 < 10) ? p.bo[32 + l15] : 0.f;
#pragma unroll
      for (int r = 0; r < 4; r++) Lr[r] = p.Lb[r0c + q * 4 + r];
    }
    __syncthreads();

    // ---- per-phase register state ----
    float creg[2][4];
#pragma unroll
    for (int ms = 0; ms < 2; ms++)
#pragma unroll
      for (int r = 0; r < 4; r++) creg[ms][r] = 0.f;
    float bias[4] = {0.f, 0.f, 0.f, 0.f};
    if (role == 1 || role == 2) {
      const float* bb = dec ? (role == 1 ? p.dec_b1 : p.dec_b2) : (role == 1 ? p.enc_b1 : p.enc_b2);
#pragma unroll
      for (int g = 0; g < 4; g++) bias[g] = bb[g * 512 + u];
    }

    // ---- per-wave wait-set for this phase ----
    const int* myp = nullptr; int myc = 0;
    if (role == 0) {
      if (w == 0) { myp = p.flg + FI(0, mi); myc = 32; }
      else if (w == 1) { myp = p.flg + FI(1, mi); myc = 32; }
    } else if (role == 1) {
      if (w == 0) { myp = p.flg + FI(0, mi); myc = 32; }
      else if (w == 1) { myp = p.flg + FI(1, mi); myc = 32; }
      else if (w == 2) { myp = p.flg + FI(2, mi); myc = 32; }
    } else if (role == 2) {
      if (w == 0) { myp = p.flg + FI(1, mi); myc = 32; }
      else if (w == 1) { myp = p.flg + FI(2, mi); myc = 32; }
      else if (w == 2 && dec) { myp = p.flg + FI(3, mi); myc = 2; }
    } else {
      if (w == 0 && dec) { myp = p.flg + FI(2, cb >> 1); myc = 32; }
    }

    grid_barrier(p.bar, p.gen);  // phase aligned; zf16/weights visible

    // decoder z A-fragments: constant over the phase — load once into registers
    bf8 zr0[8], zr1[8];
    if (role == 0 && dec) {
      const ushort_t* Az0 = p.zf16 + (rw + l15) * 256 + q * 8;
#pragma unroll
      for (int kz = 0; kz < 8; kz++) {
        zr0[kz] = *(const bf8*)(Az0 + kz * 32);
        zr1[kz] = *(const bf8*)(Az0 + 16 * 256 + kz * 32);
      }
    }

    // ---- wavefront steps (flag-synced) ----
    const int smax = dec ? T_ + 3 : T_ + 2;
    for (int s = 0; s < smax; s++) {
      pub++;
      if (myc) wait_flags(myp, myc, pub - 1);
      __builtin_amdgcn_fence(__ATOMIC_ACQUIRE, "agent");  // flash-inv L1/L2 (no wbl2)
      __syncthreads();

      const int prv = (s & 1) ^ 1, cur = s & 1;
      const int lag = (role <= 2) ? role : 3;
      const int t = s - lag;
      if (t >= 0 && t < T_) {
        if (role == 3) {
          // ======== CE: logits GEMM + online softmax ========
          int r0c = cb * 64 + w * 16;
          const ushort_t* Ar = hb[2][prv] + (size_t)(r0c + l15) * U_ + q * 8;
          f4 a3[3];
#pragma unroll
          for (int nt = 0; nt < 3; nt++) a3[nt] = (f4){0.f, 0.f, 0.f, 0.f};
#pragma unroll 4
          for (int kt = 0; kt < 16; kt++) {
            bf8 a = *(const bf8*)(Ar + kt * 32);
#pragma unroll
            for (int nt = 0; nt < 3; nt++) {
              bf8 bbf = *(const bf8*)&wlds4[nt * 1024 + kt * 64 + lane];
              a3[nt] = MFMA(a, bbf, a3[nt]);
            }
          }
#pragma unroll
          for (int r = 0; r < 4; r++) {
            int row = r0c + q * 4 + r;
            float v0 = a3[0][r] + boR0;
            float v1 = a3[1][r] + boR1;
            float v2 = (l15 < 10) ? a3[2][r] + boR2 : -3.0e38f;
            float mx = fmaxf(fmaxf(v0, v1), v2);
            mx = fmaxf(mx, __shfl_xor(mx, 1)); mx = fmaxf(mx, __shfl_xor(mx, 2));
            mx = fmaxf(mx, __shfl_xor(mx, 4)); mx = fmaxf(mx, __shfl_xor(mx, 8));
            float se = __expf(v0 - mx) + __expf(v1 - mx) + ((l15 < 10) ? __expf(v2 - mx) : 0.f);
            int yv = ytok[(w * 16 + q * 4 + r) * 133 + t];
            float py = (l15 == yv ? v0 : 0.f) + (l15 + 16 == yv ? v1 : 0.f) + (l15 + 32 == yv ? v2 : 0.f);
            se += __shfl_xor(se, 1); se += __shfl_xor(se, 2); se += __shfl_xor(se, 4); se += __shfl_xor(se, 8);
            py += __shfl_xor(py, 1); py += __shfl_xor(py, 2); py += __shfl_xor(py, 4); py += __shfl_xor(py, 8);
            if (l15 == 0 && t < Lr[r]) ce_local += mx + __logf(se) - py;
          }
        } else {
          // ======== LSTM layer step ========
          f4 acc[2][4];
#pragma unroll
          for (int ms = 0; ms < 2; ms++)
#pragma unroll
            for (int g = 0; g < 4; g++) acc[ms][g] = (f4){0.f, 0.f, 0.f, 0.f};

          const ushort_t* hin = hb[role][prv];
          ushort_t* hout = hb[role][cur];
          const ushort_t* Ah0 = hin + (size_t)(rw + l15) * U_ + q * 8;
          const ushort_t* Ah1 = Ah0 + 16 * U_;

          if (role == 0) {
            const int KT64 = KT * 64;
#pragma unroll 4
            for (int kt = 0; kt < 16; kt++) {
              bf8 a0 = *(const bf8*)(Ah0 + kt * 32);
              bf8 a1 = *(const bf8*)(Ah1 + kt * 32);
#pragma unroll
              for (int g = 0; g < 4; g++) {
                bf8 bbf = *(const bf8*)&wlds4[g * KT64 + kt * 64 + lane];
                acc[0][g] = MFMA(a0, bbf, acc[0][g]);
                acc[1][g] = MFMA(a1, bbf, acc[1][g]);
              }
            }
            if (dec) {  // z-region kt 16..23 (register-resident A)
#pragma unroll
              for (int kz = 0; kz < 8; kz++) {
#pragma unroll
                for (int g = 0; g < 4; g++) {
                  bf8 bbf = *(const bf8*)&wlds4[g * KT64 + (16 + kz) * 64 + lane];
                  acc[0][g] = MFMA(zr0[kz], bbf, acc[0][g]);
                  acc[1][g] = MFMA(zr1[kz], bbf, acc[1][g]);
                }
              }
            }
            // const region (onehot token, C, 1)
            int xv0 = tok[(w * 32 + l15) * 133 + t];
            int xv1 = tok[(w * 32 + 16 + l15) * 133 + t];
#pragma unroll
            for (int ktc = 0; ktc < 2; ktc++) {
              union { ushort_t us[8]; bf8 v; } a0u, a1u;
#pragma unroll
              for (int j = 0; j < 8; j++) {
                int id = ktc * 32 + q * 8 + j;
                ushort_t v0 = (id == xv0) ? (ushort_t)0x3F80 : (ushort_t)0;
                ushort_t v1 = (id == xv1) ? (ushort_t)0x3F80 : (ushort_t)0;
                if (id >= 42 && id < 45) { v0 = cb0[0][id - 42]; v1 = cb0[1][id - 42]; }
                if (id == 45) { v0 = 0x3F80; v1 = 0x3F80; }
                a0u.us[j] = v0; a1u.us[j] = v1;
              }
              int kt = KT - 2 + ktc;
#pragma unroll
              for (int g = 0; g < 4; g++) {
                bf8 bbf = *(const bf8*)&wlds4[g * KT64 + kt * 64 + lane];
                acc[0][g] = MFMA(a0u.v, bbf, acc[0][g]);
                acc[1][g] = MFMA(a1u.v, bbf, acc[1][g]);
              }
            }
          } else {
            const ushort_t* xin = hb[role - 1][prv];
            const ushort_t* Ax0 = xin + (size_t)(rw + l15) * U_ + q * 8;
            const ushort_t* Ax1 = Ax0 + 16 * U_;
#pragma unroll 4
            for (int kt = 0; kt < 16; kt++) {
              bf8 a0 = *(const bf8*)(Ax0 + kt * 32);
              bf8 a1 = *(const bf8*)(Ax1 + kt * 32);
#pragma unroll
              for (int g = 0; g < 4; g++) {
                bf8 bbf = *(const bf8*)&wlds4[g * 1024 + kt * 64 + lane];
                acc[0][g] = MFMA(a0, bbf, acc[0][g]);
                acc[1][g] = MFMA(a1, bbf, acc[1][g]);
              }
            }
#pragma unroll 4
            for (int kt = 0; kt < 16; kt++) {
              bf8 a0 = *(const bf8*)(Ah0 + kt * 32);
              bf8 a1 = *(const bf8*)(Ah1 + kt * 32);
#pragma unroll
              for (int g = 0; g < 4; g++) {
                bf8 bbf = *(const bf8*)&wlds4[4096 + g * 1024 + kt * 64 + lane];
                acc[0][g] = MFMA(a0, bbf, acc[0][g]);
                acc[1][g] = MFMA(a1, bbf, acc[1][g]);
              }
            }
          }

          // ---- gate pointwise; h stores write-through sc0 sc1 ----
#pragma unroll
          for (int ms = 0; ms < 2; ms++)
#pragma unroll
            for (int r = 0; r < 4; r++) {
              int row = rw + ms * 16 + q * 4 + r;
              float zi = acc[ms][0][r] + bias[0];
              float zf = acc[ms][1][r] + bias[1];
              float zg = acc[ms][2][r] + bias[2];
              float zo = acc[ms][3][r] + bias[3];
              float cp = creg[ms][r];
              float cn = sigf(zf) * cp + sigf(zi) * tanhfast(zg);
              float hn = sigf(zo) * tanhfast(cn);
              creg[ms][r] = cn;
              st_wt_b16(&hout[(size_t)row * U_ + u], f2bf(hn));
              if (!dec && role == 2 && t == T_ - 1) p.c2g[(size_t)row * U_ + u] = cn;
            }
        }
      }
      wait_vm0();        // all write-through stores ACKed at coherence point
      __syncthreads();   // ... for every wave of the block
      if (tid == 0) st_wt_b32(p.flg + pubidx, (unsigned int)pub);
    }
  }

  // ---- CE flush, final reduce ----
  if (role == 3 && l15 == 0) atomicAdd(p.sums + 0, ce_local);
  grid_barrier(p.bar, p.gen);
  if (b == 0 && tid == 0) {
    float recon = p.sums[0] * (1.f / ((float)B_ * (float)T_));
    float latent = -0.5f * p.sums[1] * (1.f / ((float)B_ * (float)LAT_));
    p.out[0] = recon + latent;
    p.out[1] = recon;
    p.out[2] = latent;
  }
}

// ---------------------------------------------------------------------------
extern "C" void kernel_launch(void* const* d_in, const int* in_sizes, int n_in,
                              void* d_out, int out_size, void* d_ws, size_t ws_size,
                              hipStream_t stream) {
  const int*   X       = (const int*)d_in[0];
  const int*   Y       = (const int*)d_in[1];
  const float* C       = (const float*)d_in[2];
  const int*   L       = (const int*)d_in[3];
  const float* eps     = (const float*)d_in[4];
  const float* emb_enc = (const float*)d_in[5];
  const float* emb_dec = (const float*)d_in[6];
  const float* enc_k0  = (const float*)d_in[7];
  const float* enc_rk0 = (const float*)d_in[8];
  const float* enc_b0  = (const float*)d_in[9];
  const float* enc_k1  = (const float*)d_in[10];
  const float* enc_rk1 = (const float*)d_in[11];
  const float* enc_b1  = (const float*)d_in[12];
  const float* enc_k2  = (const float*)d_in[13];
  const float* enc_rk2 = (const float*)d_in[14];
  const float* enc_b2  = (const float*)d_in[15];
  const float* dec_k0  = (const float*)d_in[16];
  const float* dec_rk0 = (const float*)d_in[17];
  const float* dec_b0  = (const float*)d_in[18];
  const float* dec_k1  = (const float*)d_in[19];
  const float* dec_rk1 = (const float*)d_in[20];
  const float* dec_b1  = (const float*)d_in[21];
  const float* dec_k2  = (const float*)d_in[22];
  const float* dec_rk2 = (const float*)d_in[23];
  const float* dec_b2  = (const float*)d_in[24];
  const float* Wm      = (const float*)d_in[25];
  const float* bm      = (const float*)d_in[26];
  const float* Ws      = (const float*)d_in[27];
  const float* bs      = (const float*)d_in[28];
  const float* Wo      = (const float*)d_in[29];
  const float* bo      = (const float*)d_in[30];
  float* out = (float*)d_out;
  (void)in_sizes; (void)n_in; (void)out_size; (void)ws_size;

  char* wsb = (char*)d_ws;
  size_t o = 0;
  auto take = [&](size_t bytes) -> char* { char* p = wsb + o; o += (bytes + 255) & ~(size_t)255; return p; };

  // ---- zeroed region ----
  ushort_t* hE[3][2]; ushort_t* hD[3][2];
  for (int l = 0; l < 3; l++) for (int pi = 0; pi < 2; pi++) hE[l][pi] = (ushort_t*)take((size_t)B_ * U_ * 2);
  for (int l = 0; l < 3; l++) for (int pi = 0; pi < 2; pi++) hD[l][pi] = (ushort_t*)take((size_t)B_ * U_ * 2);
  float* c2g  = (float*)take((size_t)B_ * U_ * 4);
  ushort_t* zf16 = (ushort_t*)take((size_t)B_ * 256 * 2);
  float* sums = (float*)take(8);
  int* bar = (int*)take(4);
  int* gen = (int*)take(4);
  int* flg = (int*)take(4 * 2 * 32 * 4);
  size_t zero_bytes = o;
  // ---- recomputed-per-call region ----
  ushort_t* swz = (ushort_t*)take((size_t)1412096 * 16);
  float* tabE = (float*)take((size_t)V_ * G4_ * 4);
  float* tabD = (float*)take((size_t)V_ * G4_ * 4);

  hipMemsetAsync(wsb, 0, zero_bytes, stream);
  table_kernel<<<V_, 256, 0, stream>>>(emb_enc, enc_k0, 0, tabE);
  table_kernel<<<V_, 256, 0, stream>>>(emb_dec, dec_k0, 200, tabD);

  SwzSrc ss;
  ss.enc_rk0 = enc_rk0; ss.enc_k0 = enc_k0; ss.enc_b0 = enc_b0;
  ss.dec_rk0 = dec_rk0; ss.dec_k0 = dec_k0; ss.dec_b0 = dec_b0;
  ss.tabE = tabE; ss.tabD = tabD;
  ss.encK1 = enc_k1; ss.encR1 = enc_rk1; ss.encK2 = enc_k2; ss.encR2 = enc_rk2;
  ss.decK1 = dec_k1; ss.decR1 = dec_rk1; ss.decK2 = dec_k2; ss.decR2 = dec_rk2;
  ss.Wo = Wo; ss.dst = swz;
  swz_ext_kernel<<<1283, 256, 0, stream>>>(ss);

  PP pp;
  pp.swz = swz;
  pp.he0a = hE[0][0]; pp.he0b = hE[0][1]; pp.he1a = hE[1][0]; pp.he1b = hE[1][1];
  pp.he2a = hE[2][0]; pp.he2b = hE[2][1];
  pp.hd0a = hD[0][0]; pp.hd0b = hD[0][1]; pp.hd1a = hD[1][0]; pp.hd1b = hD[1][1];
  pp.hd2a = hD[2][0]; pp.hd2b = hD[2][1];
  pp.c2g = c2g; pp.zf16 = zf16; pp.sums = sums; pp.bar = bar; pp.gen = gen; pp.flg = flg; pp.out = out;
  pp.enc_b1 = enc_b1; pp.enc_b2 = enc_b2; pp.dec_b1 = dec_b1; pp.dec_b2 = dec_b2;
  pp.Wm = Wm; pp.bm = bm; pp.Ws = Ws; pp.bs = bs; pp.eps = eps; pp.C = C; pp.bo = bo;
  pp.X = X; pp.Y = Y; pp.Lb = L;
  persist<<<NBLK, 256, 0, stream>>>(pp);
}